// Round 1
// baseline (1860.954 us; speedup 1.0000x reference)
//
#include <hip/hip_runtime.h>
#include <cstddef>
#include <cstdint>

// Problem constants
#define B_   16
#define L_   256
#define DM_  512
#define DI_  1024
#define N_   16
#define R_   32
#define K_   4
#define ROWS (B_ * L_)          // 4096

// ---------------- workspace layout (floats) ----------------
#define WS_XZ      0u                       // ROWS * 2*DI = 8388608
#define WS_U       8388608u                 // ROWS * DI   = 4194304
#define WS_P1      12582912u                // ROWS * 64   = 262144
#define WS_P2      12845056u                // ROWS * 64   = 262144
#define WS_DRS     13107200u                // ROWS * 32   = 131072
#define WS_BS      13238272u                // ROWS * DI
#define WS_CS      17432576u                // ROWS * DI
#define WS_DELTA   21626880u                // ROWS * DI
#define WS_DELTAB  25821184u                // ROWS * DI
#define WS_S1      30015488u                // ROWS
#define WS_S2      30019584u                // ROWS
#define WS_XK1     30023680u                // B*DI = 16384
#define WS_S0SP    30040064u                // ROWS (B*L)
#define WS_YACC    30044160u                // ROWS * DI
// total 34238464 floats = ~137 MB

// ---------------- generic fp32 GEMM: C = A @ W (+ optional softplus(x+bias)) ----------------
#define BM 128
#define BN 128
#define BK 16

__global__ __launch_bounds__(256)
void gemm_f32(const float* __restrict__ A, const float* __restrict__ W,
              float* __restrict__ C, const float* __restrict__ bias,
              int M, int N, int K, int lda, int ldw, int ldc, int mode)
{
    __shared__ float As[BK][BM + 4];
    __shared__ float Ws[BK][BN + 4];
    const int tid = threadIdx.x;
    const int bn = blockIdx.x * BN;
    const int bm = blockIdx.y * BM;

    const int arow = tid >> 2;            // 0..63
    const int ak   = (tid & 3) * 4;       // 0,4,8,12
    const int wrow = tid >> 4;            // 0..15
    const int wc   = (tid & 15) * 8;      // 0..120

    const int tx = tid & 15, ty = tid >> 4;

    float acc[8][8];
    #pragma unroll
    for (int i = 0; i < 8; ++i)
        #pragma unroll
        for (int j = 0; j < 8; ++j) acc[i][j] = 0.f;

    for (int kt = 0; kt < K; kt += BK) {
        // ---- load A tile (BM x BK), transposed into As[k][m]
        #pragma unroll
        for (int h = 0; h < 2; ++h) {
            int r = arow + h * 64;
            int grow = bm + r;
            float4 v = make_float4(0.f, 0.f, 0.f, 0.f);
            if (grow < M)
                v = *reinterpret_cast<const float4*>(A + (size_t)grow * lda + kt + ak);
            As[ak + 0][r] = v.x; As[ak + 1][r] = v.y;
            As[ak + 2][r] = v.z; As[ak + 3][r] = v.w;
        }
        // ---- load W tile (BK x BN)
        #pragma unroll
        for (int h = 0; h < 2; ++h) {
            int col = wc + h * 4;
            int gcol = bn + col;
            float4 v;
            if (gcol + 3 < N) {
                v = *reinterpret_cast<const float4*>(W + (size_t)(kt + wrow) * ldw + gcol);
            } else {
                float t0 = (gcol + 0 < N) ? W[(size_t)(kt + wrow) * ldw + gcol + 0] : 0.f;
                float t1 = (gcol + 1 < N) ? W[(size_t)(kt + wrow) * ldw + gcol + 1] : 0.f;
                float t2 = (gcol + 2 < N) ? W[(size_t)(kt + wrow) * ldw + gcol + 2] : 0.f;
                float t3 = (gcol + 3 < N) ? W[(size_t)(kt + wrow) * ldw + gcol + 3] : 0.f;
                v = make_float4(t0, t1, t2, t3);
            }
            *reinterpret_cast<float4*>(&Ws[wrow][col]) = v;
        }
        __syncthreads();
        #pragma unroll
        for (int k = 0; k < BK; ++k) {
            float av[8], wv[8];
            #pragma unroll
            for (int i = 0; i < 8; ++i) av[i] = As[k][ty * 8 + i];
            #pragma unroll
            for (int j = 0; j < 8; ++j) wv[j] = Ws[k][tx * 8 + j];
            #pragma unroll
            for (int i = 0; i < 8; ++i)
                #pragma unroll
                for (int j = 0; j < 8; ++j)
                    acc[i][j] = fmaf(av[i], wv[j], acc[i][j]);
        }
        __syncthreads();
    }

    #pragma unroll
    for (int i = 0; i < 8; ++i) {
        int r = bm + ty * 8 + i;
        if (r >= M) break;
        #pragma unroll
        for (int j = 0; j < 8; ++j) {
            int cc = bn + tx * 8 + j;
            if (cc < N) {
                float v = acc[i][j];
                if (mode == 1) {
                    v += bias[cc];
                    v = fmaxf(v, 0.f) + log1pf(expf(-fabsf(v)));  // stable softplus
                }
                C[(size_t)r * ldc + cc] = v;
            }
        }
    }
}

// ---------------- causal depthwise conv (K=4) + SiLU ----------------
__global__ __launch_bounds__(256)
void conv_silu(const float* __restrict__ xz, const float* __restrict__ conv_w,
               const float* __restrict__ conv_b, float* __restrict__ u)
{
    int idx = blockIdx.x * 256 + threadIdx.x;     // over ROWS*DI
    if (idx >= ROWS * DI_) return;
    int d  = idx & (DI_ - 1);
    int rl = idx >> 10;
    int l  = rl & (L_ - 1);
    float acc = conv_b[d];
    #pragma unroll
    for (int k = 0; k < K_; ++k) {
        int ll = l + k - (K_ - 1);
        if (ll >= 0)
            acc = fmaf(xz[(size_t)(rl + k - (K_ - 1)) * (2 * DI_) + d], conv_w[d * K_ + k], acc);
    }
    u[idx] = acc / (1.f + expf(-acc));            // silu
}

// ---------------- yacc = res + u*(D + D_b + D_s) ----------------
__global__ __launch_bounds__(256)
void init_yacc(const float* __restrict__ xz, const float* __restrict__ u,
               const float* __restrict__ D, const float* __restrict__ Db,
               const float* __restrict__ Ds, float* __restrict__ yacc)
{
    int idx = blockIdx.x * 256 + threadIdx.x;
    if (idx >= ROWS * DI_) return;
    int d = idx & (DI_ - 1);
    int row = idx >> 10;
    yacc[idx] = xz[(size_t)row * (2 * DI_) + DI_ + d] + u[idx] * (D[d] + Db[d] + Ds[d]);
}

// ---------------- spatial scalars: S1 = sum_d softplus(drs@W+b), S2 = sum_d sp*u ----------------
__global__ __launch_bounds__(256)
void spatial_scalars(const float* __restrict__ drs, const float* __restrict__ Wt,
                     const float* __restrict__ bias, const float* __restrict__ u,
                     float* __restrict__ S1, float* __restrict__ S2)
{
    int r = blockIdx.x;                 // 0..ROWS-1
    int tid = threadIdx.x;
    __shared__ float drsh[R_];
    if (tid < R_) drsh[tid] = drs[r * R_ + tid];
    __syncthreads();
    float s1 = 0.f, s2 = 0.f;
    #pragma unroll
    for (int j = 0; j < 4; ++j) {
        int d = tid + 256 * j;
        float acc = bias[d];
        #pragma unroll
        for (int k = 0; k < R_; ++k)
            acc = fmaf(drsh[k], Wt[k * DI_ + d], acc);
        float sp = fmaxf(acc, 0.f) + log1pf(expf(-fabsf(acc)));
        s1 += sp;
        s2 = fmaf(sp, u[(size_t)r * DI_ + d], s2);
    }
    #pragma unroll
    for (int off = 32; off; off >>= 1) {
        s1 += __shfl_down(s1, off, 64);
        s2 += __shfl_down(s2, off, 64);
    }
    __shared__ float red[2][4];
    int wave = tid >> 6, lane = tid & 63;
    if (lane == 0) { red[0][wave] = s1; red[1][wave] = s2; }
    __syncthreads();
    if (tid == 0) {
        S1[r] = red[0][0] + red[0][1] + red[0][2] + red[0][3];
        S2[r] = red[1][0] + red[1][1] + red[1][2] + red[1][3];
    }
}

// ---------------- temporal scan (fwd/bwd), adds einsum output into yacc ----------------
__global__ __launch_bounds__(256)
void temporal_scan(const float* __restrict__ delta, const float* __restrict__ p,
                   const float* __restrict__ u, const float* __restrict__ A_log,
                   const float* __restrict__ xk1, const float* __restrict__ key2,
                   float* __restrict__ yacc, int reverse)
{
    int tid = threadIdx.x;
    int n  = tid & 15;
    int dl = tid >> 4;                        // 0..15
    int b  = blockIdx.y;
    int d  = blockIdx.x * 16 + dl;
    float An = -expf(A_log[n]);
    float k2 = key2[n];
    float s = xk1[b * DI_ + d] * k2;
    int rowbase = b * L_;
    for (int t = 0; t < L_; ++t) {
        int l = reverse ? (L_ - 1 - t) : t;
        int row = rowbase + l;
        float dv = delta[(size_t)row * DI_ + d];
        float uv = u[(size_t)row * DI_ + d];
        float Bv = p[row * 64 + 32 + n];
        float Cv = p[row * 64 + 48 + n];
        float dA = expf(An * dv);
        s = fmaf(dA, s, dv * Bv * uv);
        float part = s * Cv;
        part += __shfl_xor(part, 1, 16);
        part += __shfl_xor(part, 2, 16);
        part += __shfl_xor(part, 4, 16);
        part += __shfl_xor(part, 8, 16);
        if (n == 0) yacc[(size_t)row * DI_ + d] += part;
    }
}

// ---------------- spatial scan over channel axis d (wave-parallel affine scan) ----------------
__global__ __launch_bounds__(256)
void spatial_scan(const float* __restrict__ S1b, const float* __restrict__ S2b,
                  const float* __restrict__ Bs, const float* __restrict__ Cs,
                  const float* __restrict__ A_s_log, const float* __restrict__ s0sp,
                  float* __restrict__ yacc)
{
    int wave = threadIdx.x >> 6;
    int lane = threadIdx.x & 63;
    int r = blockIdx.x * 4 + wave;            // row (b*L + l)
    float s1 = S1b[r], s2 = S2b[r];
    int dbase = lane * 16;

    float a[16], bb[16];
    float Aloc = 1.f, Bloc = 0.f;
    #pragma unroll
    for (int j = 0; j < 16; ++j) {
        int d = dbase + j;
        float As = -expf(A_s_log[d]);
        float av = expf(s1 * As);
        float bv = s2 * Bs[(size_t)r * DI_ + d];
        a[j] = av; bb[j] = bv;
        Bloc = fmaf(av, Bloc, bv);
        Aloc *= av;
    }
    // inclusive wave scan (combine current-after with previous-before)
    #pragma unroll
    for (int off = 1; off < 64; off <<= 1) {
        float Ap = __shfl_up(Aloc, off, 64);
        float Bp = __shfl_up(Bloc, off, 64);
        if (lane >= off) { Bloc = fmaf(Aloc, Bp, Bloc); Aloc *= Ap; }
    }
    // exclusive prefix
    float Aex = __shfl_up(Aloc, 1, 64);
    float Bex = __shfl_up(Bloc, 1, 64);
    if (lane == 0) { Aex = 1.f; Bex = 0.f; }
    float s = fmaf(Aex, s0sp[r], Bex);
    #pragma unroll
    for (int j = 0; j < 16; ++j) {
        int d = dbase + j;
        s = fmaf(a[j], s, bb[j]);
        yacc[(size_t)r * DI_ + d] += s * Cs[(size_t)r * DI_ + d];
    }
}

// ---------------- launcher ----------------
static inline void launch_gemm(const float* A, const float* W, float* C, const float* bias,
                               int M, int N, int K, int lda, int ldw, int ldc, int mode,
                               hipStream_t stream)
{
    dim3 grid((N + BN - 1) / BN, (M + BM - 1) / BM);
    gemm_f32<<<grid, 256, 0, stream>>>(A, W, C, bias, M, N, K, lda, ldw, ldc, mode);
}

extern "C" void kernel_launch(void* const* d_in, const int* in_sizes, int n_in,
                              void* d_out, int out_size, void* d_ws, size_t ws_size,
                              hipStream_t stream)
{
    const float* x         = (const float*)d_in[0];
    const float* x_key     = (const float*)d_in[1];
    const float* in_proj_w = (const float*)d_in[2];
    const float* conv_w    = (const float*)d_in[3];
    const float* conv_b    = (const float*)d_in[4];
    const float* x_proj_w  = (const float*)d_in[5];
    const float* x_proj_b_w= (const float*)d_in[6];
    const float* x_proj_s_w= (const float*)d_in[7];
    const float* dt_w      = (const float*)d_in[8];
    const float* dt_bias   = (const float*)d_in[9];
    const float* dt_b_w    = (const float*)d_in[10];
    const float* dt_b_bias = (const float*)d_in[11];
    const float* dt_s_w    = (const float*)d_in[12];
    const float* dt_s_bias = (const float*)d_in[13];
    const float* key1_w    = (const float*)d_in[14];
    const float* key2_w    = (const float*)d_in[15];
    const float* keys_w    = (const float*)d_in[16];
    const float* A_log     = (const float*)d_in[17];
    const float* A_b_log   = (const float*)d_in[18];
    const float* A_s_log   = (const float*)d_in[19];
    const float* D         = (const float*)d_in[20];
    const float* D_b       = (const float*)d_in[21];
    const float* D_s       = (const float*)d_in[22];
    const float* out_proj_w= (const float*)d_in[23];

    float* ws = (float*)d_ws;
    float* xz    = ws + WS_XZ;
    float* u     = ws + WS_U;
    float* p1    = ws + WS_P1;
    float* p2    = ws + WS_P2;
    float* drs   = ws + WS_DRS;
    float* Bs    = ws + WS_BS;
    float* Cs    = ws + WS_CS;
    float* delta = ws + WS_DELTA;
    float* deltab= ws + WS_DELTAB;
    float* S1    = ws + WS_S1;
    float* S2    = ws + WS_S2;
    float* xk1   = ws + WS_XK1;
    float* s0sp  = ws + WS_S0SP;
    float* yacc  = ws + WS_YACC;
    float* out   = (float*)d_out;

    // 1. xz = x @ in_proj_w
    launch_gemm(x, in_proj_w, xz, nullptr, ROWS, 2 * DI_, DM_, DM_, 2 * DI_, 2 * DI_, 0, stream);
    // 2. u = silu(causal depthwise conv(xc) + b)
    conv_silu<<<(ROWS * DI_) / 256, 256, 0, stream>>>(xz, conv_w, conv_b, u);
    // 3. projections
    launch_gemm(u, x_proj_w,   p1,  nullptr, ROWS, 64,  DI_, DI_, 64,   64,  0, stream);
    launch_gemm(u, x_proj_b_w, p2,  nullptr, ROWS, 64,  DI_, DI_, 64,   64,  0, stream);
    launch_gemm(u, x_proj_s_w,        drs, nullptr, ROWS, 32,   DI_, DI_, 2080, 32,   0, stream);
    launch_gemm(u, x_proj_s_w + 32,   Bs,  nullptr, ROWS, DI_,  DI_, DI_, 2080, DI_,  0, stream);
    launch_gemm(u, x_proj_s_w + 1056, Cs,  nullptr, ROWS, DI_,  DI_, DI_, 2080, DI_,  0, stream);
    // 4. delta = softplus(dr @ dt_w + bias)
    launch_gemm(p1, dt_w,   delta,  dt_bias,   ROWS, DI_, R_, 64, DI_, DI_, 1, stream);
    launch_gemm(p2, dt_b_w, deltab, dt_b_bias, ROWS, DI_, R_, 64, DI_, DI_, 1, stream);
    // 5. spatial scalars (delta_s never materialized)
    spatial_scalars<<<ROWS, 256, 0, stream>>>(drs, dt_s_w, dt_s_bias, u, S1, S2);
    // 6. initial states
    launch_gemm(x_key, key1_w, xk1,  nullptr, B_, DI_, DM_, DM_, DI_, DI_, 0, stream);
    launch_gemm(x_key, keys_w, s0sp, nullptr, B_, L_,  DM_, DM_, L_,  L_,  0, stream);
    // 7. yacc = res + u*(D+Db+Ds)
    init_yacc<<<(ROWS * DI_) / 256, 256, 0, stream>>>(xz, u, D, D_b, D_s, yacc);
    // 8. temporal scans (fwd, bwd)
    {
        dim3 grid(DI_ / 16, B_);
        temporal_scan<<<grid, 256, 0, stream>>>(delta,  p1, u, A_log,   xk1, key2_w, yacc, 0);
        temporal_scan<<<grid, 256, 0, stream>>>(deltab, p2, u, A_b_log, xk1, key2_w, yacc, 1);
    }
    // 9. spatial scan over d
    spatial_scan<<<ROWS / 4, 256, 0, stream>>>(S1, S2, Bs, Cs, A_s_log, s0sp, yacc);
    // 10. out = yacc @ out_proj_w
    launch_gemm(yacc, out_proj_w, out, nullptr, ROWS, DM_, DI_, DI_, DM_, DM_, 0, stream);
}

// Round 5
// 1337.620 us; speedup vs baseline: 1.3912x; 1.3912x over previous
//
#include <hip/hip_runtime.h>
#include <cstddef>
#include <cstdint>

// Problem constants
#define B_   16
#define L_   256
#define DM_  512
#define DI_  1024
#define N_   16
#define R_   32
#define K_   4
#define ROWS (B_ * L_)          // 4096

typedef __attribute__((ext_vector_type(8))) short bf16x8;
typedef __attribute__((ext_vector_type(4))) float f32x4;

__device__ inline unsigned short f2bf(float x) {
    unsigned u = __float_as_uint(x);
    unsigned r = u + 0x7FFFu + ((u >> 16) & 1u);
    return (unsigned short)(r >> 16);
}
__device__ inline float bf2f(unsigned short h) {
    return __uint_as_float(((unsigned)h) << 16);
}

// ---------------- generic fp32 GEMM (small matrices): C = A @ W (+softplus) ----------------
#define BM 128
#define BN 128
#define BK 16

__global__ __launch_bounds__(256)
void gemm_f32(const float* __restrict__ A, const float* __restrict__ W,
              float* __restrict__ C, const float* __restrict__ bias,
              int M, int N, int K, int lda, int ldw, int ldc, int mode)
{
    __shared__ float As[BK][BM + 4];
    __shared__ float Ws[BK][BN + 4];
    const int tid = threadIdx.x;
    const int bn = blockIdx.x * BN;
    const int bm = blockIdx.y * BM;

    const int arow = tid >> 2;
    const int ak   = (tid & 3) * 4;
    const int wrow = tid >> 4;
    const int wc   = (tid & 15) * 8;
    const int tx = tid & 15, ty = tid >> 4;

    float acc[8][8];
    #pragma unroll
    for (int i = 0; i < 8; ++i)
        #pragma unroll
        for (int j = 0; j < 8; ++j) acc[i][j] = 0.f;

    for (int kt = 0; kt < K; kt += BK) {
        #pragma unroll
        for (int h = 0; h < 2; ++h) {
            int r = arow + h * 64;
            int grow = bm + r;
            float4 v = make_float4(0.f, 0.f, 0.f, 0.f);
            if (grow < M)
                v = *reinterpret_cast<const float4*>(A + (size_t)grow * lda + kt + ak);
            As[ak + 0][r] = v.x; As[ak + 1][r] = v.y;
            As[ak + 2][r] = v.z; As[ak + 3][r] = v.w;
        }
        #pragma unroll
        for (int h = 0; h < 2; ++h) {
            int col = wc + h * 4;
            int gcol = bn + col;
            float4 v;
            if (gcol + 3 < N) {
                v = *reinterpret_cast<const float4*>(W + (size_t)(kt + wrow) * ldw + gcol);
            } else {
                float t0 = (gcol + 0 < N) ? W[(size_t)(kt + wrow) * ldw + gcol + 0] : 0.f;
                float t1 = (gcol + 1 < N) ? W[(size_t)(kt + wrow) * ldw + gcol + 1] : 0.f;
                float t2 = (gcol + 2 < N) ? W[(size_t)(kt + wrow) * ldw + gcol + 2] : 0.f;
                float t3 = (gcol + 3 < N) ? W[(size_t)(kt + wrow) * ldw + gcol + 3] : 0.f;
                v = make_float4(t0, t1, t2, t3);
            }
            *reinterpret_cast<float4*>(&Ws[wrow][col]) = v;
        }
        __syncthreads();
        #pragma unroll
        for (int k = 0; k < BK; ++k) {
            float av[8], wv[8];
            #pragma unroll
            for (int i = 0; i < 8; ++i) av[i] = As[k][ty * 8 + i];
            #pragma unroll
            for (int j = 0; j < 8; ++j) wv[j] = Ws[k][tx * 8 + j];
            #pragma unroll
            for (int i = 0; i < 8; ++i)
                #pragma unroll
                for (int j = 0; j < 8; ++j)
                    acc[i][j] = fmaf(av[i], wv[j], acc[i][j]);
        }
        __syncthreads();
    }

    #pragma unroll
    for (int i = 0; i < 8; ++i) {
        int r = bm + ty * 8 + i;
        if (r >= M) break;
        #pragma unroll
        for (int j = 0; j < 8; ++j) {
            int cc = bn + tx * 8 + j;
            if (cc < N) {
                float v = acc[i][j];
                if (mode == 1) {
                    v += bias[cc];
                    v = fmaxf(v, 0.f) + log1pf(expf(-fabsf(v)));
                }
                C[(size_t)r * ldc + cc] = v;
            }
        }
    }
}

// ---------------- split-bf16 MFMA GEMM: C = (Ahi+Alo) @ W, W transposed hi/lo ----------------
#define SBM 128
#define SBN 128
#define SBK 32
#define SLDK 40   // padded LDS row (bf16): 80B rows -> 2-way conflicts only (free)

__global__ __launch_bounds__(256)
void gemm_split_mfma(const unsigned short* __restrict__ Ahi, const unsigned short* __restrict__ Alo,
                     const unsigned short* __restrict__ Bthi, const unsigned short* __restrict__ Btlo,
                     float* __restrict__ C, int M, int N, int K)
{
    __shared__ unsigned short sAh[SBM][SLDK], sAl[SBM][SLDK];
    __shared__ unsigned short sBh[SBN][SLDK], sBl[SBN][SLDK];
    const int tid = threadIdx.x;
    const int bm = blockIdx.y * SBM;
    const int bn = blockIdx.x * SBN;
    const int w = tid >> 6, lane = tid & 63;
    const int wr = w >> 1, wc = w & 1;
    const int lr = lane & 15, kg = lane >> 4;   // kg = k-group 0..3

    f32x4 acc[4][4];
    #pragma unroll
    for (int i = 0; i < 4; ++i)
        #pragma unroll
        for (int j = 0; j < 4; ++j) acc[i][j] = (f32x4){0.f, 0.f, 0.f, 0.f};

    const int srow0 = tid >> 2;          // 0..63
    const int sks   = (tid & 3) * 8;     // bf16 k-offset 0,8,16,24

    for (int kt = 0; kt < K; kt += SBK) {
        #pragma unroll
        for (int h = 0; h < 2; ++h) {
            int r = srow0 + h * 64;
            size_t ga = (size_t)(bm + r) * K + kt + sks;
            size_t gb = (size_t)(bn + r) * K + kt + sks;
            uint4 vah = *reinterpret_cast<const uint4*>(Ahi + ga);
            uint4 val = *reinterpret_cast<const uint4*>(Alo + ga);
            uint4 vbh = *reinterpret_cast<const uint4*>(Bthi + gb);
            uint4 vbl = *reinterpret_cast<const uint4*>(Btlo + gb);
            *reinterpret_cast<uint4*>(&sAh[r][sks]) = vah;
            *reinterpret_cast<uint4*>(&sAl[r][sks]) = val;
            *reinterpret_cast<uint4*>(&sBh[r][sks]) = vbh;
            *reinterpret_cast<uint4*>(&sBl[r][sks]) = vbl;
        }
        __syncthreads();

        bf16x8 ah[4], al[4], bh[4], bl[4];
        #pragma unroll
        for (int i = 0; i < 4; ++i) {
            ah[i] = *reinterpret_cast<const bf16x8*>(&sAh[wr * 64 + i * 16 + lr][kg * 8]);
            al[i] = *reinterpret_cast<const bf16x8*>(&sAl[wr * 64 + i * 16 + lr][kg * 8]);
            bh[i] = *reinterpret_cast<const bf16x8*>(&sBh[wc * 64 + i * 16 + lr][kg * 8]);
            bl[i] = *reinterpret_cast<const bf16x8*>(&sBl[wc * 64 + i * 16 + lr][kg * 8]);
        }
        #pragma unroll
        for (int i = 0; i < 4; ++i)
            #pragma unroll
            for (int j = 0; j < 4; ++j) {
                acc[i][j] = __builtin_amdgcn_mfma_f32_16x16x32_bf16(ah[i], bh[j], acc[i][j], 0, 0, 0);
                acc[i][j] = __builtin_amdgcn_mfma_f32_16x16x32_bf16(ah[i], bl[j], acc[i][j], 0, 0, 0);
                acc[i][j] = __builtin_amdgcn_mfma_f32_16x16x32_bf16(al[i], bh[j], acc[i][j], 0, 0, 0);
            }
        __syncthreads();
    }

    // C/D layout (m89-verified): col = lane&15, row = (lane>>4)*4 + reg
    #pragma unroll
    for (int i = 0; i < 4; ++i)
        #pragma unroll
        for (int j = 0; j < 4; ++j) {
            int col = bn + wc * 64 + j * 16 + lr;
            int rb  = bm + wr * 64 + i * 16 + kg * 4;
            #pragma unroll
            for (int r = 0; r < 4; ++r)
                C[(size_t)(rb + r) * N + col] = acc[i][j][r];
        }
}

// ---------------- fp32 -> (hi,lo) bf16, elementwise ----------------
__global__ __launch_bounds__(256)
void split_f32(const float* __restrict__ in, unsigned short* __restrict__ hi,
               unsigned short* __restrict__ lo, int n4)
{
    int i = blockIdx.x * 256 + threadIdx.x;
    if (i >= n4) return;
    float4 v = reinterpret_cast<const float4*>(in)[i];
    ushort4 h, l;
    h.x = f2bf(v.x); l.x = f2bf(v.x - bf2f(h.x));
    h.y = f2bf(v.y); l.y = f2bf(v.y - bf2f(h.y));
    h.z = f2bf(v.z); l.z = f2bf(v.z - bf2f(h.z));
    h.w = f2bf(v.w); l.w = f2bf(v.w - bf2f(h.w));
    reinterpret_cast<ushort4*>(hi)[i] = h;
    reinterpret_cast<ushort4*>(lo)[i] = l;
}

// ---------------- fp32 [rows][ldw] -> transposed (hi,lo) bf16 [cols][rows] ----------------
__global__ __launch_bounds__(256)
void split_transpose(const float* __restrict__ W, int ldw, int rows, int cols,
                     unsigned short* __restrict__ Thi, unsigned short* __restrict__ Tlo)
{
    __shared__ float t[32][33];
    int k0 = blockIdx.y * 32, n0 = blockIdx.x * 32;
    int tx = threadIdx.x, ty = threadIdx.y;      // 32 x 8
    #pragma unroll
    for (int i = 0; i < 4; ++i)
        t[ty + i * 8][tx] = W[(size_t)(k0 + ty + i * 8) * ldw + n0 + tx];
    __syncthreads();
    #pragma unroll
    for (int i = 0; i < 4; ++i) {
        int n = ty + i * 8;
        float v = t[tx][n];
        unsigned short h = f2bf(v);
        Thi[(size_t)(n0 + n) * rows + k0 + tx] = h;
        Tlo[(size_t)(n0 + n) * rows + k0 + tx] = f2bf(v - bf2f(h));
    }
}

// ---------------- causal depthwise conv (K=4) + SiLU ----------------
__global__ __launch_bounds__(256)
void conv_silu(const float* __restrict__ xz, const float* __restrict__ conv_w,
               const float* __restrict__ conv_b, float* __restrict__ u)
{
    int idx = blockIdx.x * 256 + threadIdx.x;
    if (idx >= ROWS * DI_) return;
    int d  = idx & (DI_ - 1);
    int rl = idx >> 10;
    int l  = rl & (L_ - 1);
    float acc = conv_b[d];
    #pragma unroll
    for (int k = 0; k < K_; ++k) {
        int ll = l + k - (K_ - 1);
        if (ll >= 0)
            acc = fmaf(xz[(size_t)(rl + k - (K_ - 1)) * (2 * DI_) + d], conv_w[d * K_ + k], acc);
    }
    u[idx] = acc / (1.f + expf(-acc));
}

// ---------------- yacc = res + u*(D + D_b + D_s) ----------------
__global__ __launch_bounds__(256)
void init_yacc(const float* __restrict__ xz, const float* __restrict__ u,
               const float* __restrict__ D, const float* __restrict__ Db,
               const float* __restrict__ Ds, float* __restrict__ yacc)
{
    int idx = blockIdx.x * 256 + threadIdx.x;
    if (idx >= ROWS * DI_) return;
    int d = idx & (DI_ - 1);
    int row = idx >> 10;
    yacc[idx] = xz[(size_t)row * (2 * DI_) + DI_ + d] + u[idx] * (D[d] + Db[d] + Ds[d]);
}

// ---------------- spatial scalars ----------------
__global__ __launch_bounds__(256)
void spatial_scalars(const float* __restrict__ drs, const float* __restrict__ Wt,
                     const float* __restrict__ bias, const float* __restrict__ u,
                     float* __restrict__ S1, float* __restrict__ S2)
{
    int r = blockIdx.x;
    int tid = threadIdx.x;
    __shared__ float drsh[R_];
    if (tid < R_) drsh[tid] = drs[r * R_ + tid];
    __syncthreads();
    float s1 = 0.f, s2 = 0.f;
    #pragma unroll
    for (int j = 0; j < 4; ++j) {
        int d = tid + 256 * j;
        float acc = bias[d];
        #pragma unroll
        for (int k = 0; k < R_; ++k)
            acc = fmaf(drsh[k], Wt[k * DI_ + d], acc);
        float sp = fmaxf(acc, 0.f) + log1pf(expf(-fabsf(acc)));
        s1 += sp;
        s2 = fmaf(sp, u[(size_t)r * DI_ + d], s2);
    }
    #pragma unroll
    for (int off = 32; off; off >>= 1) {
        s1 += __shfl_down(s1, off, 64);
        s2 += __shfl_down(s2, off, 64);
    }
    __shared__ float red[2][4];
    int wave = tid >> 6, lane = tid & 63;
    if (lane == 0) { red[0][wave] = s1; red[1][wave] = s2; }
    __syncthreads();
    if (tid == 0) {
        S1[r] = red[0][0] + red[0][1] + red[0][2] + red[0][3];
        S2[r] = red[1][0] + red[1][1] + red[1][2] + red[1][3];
    }
}

// ---------------- temporal scans, LDS-chunked + double-buffered, both dirs in one launch ----------------
#define CH 64
#define NCH (L_ / CH)

__global__ __launch_bounds__(256)
void temporal_scan2(const float* __restrict__ delta_f, const float* __restrict__ p_f,
                    const float* __restrict__ A_log_f,
                    const float* __restrict__ delta_b, const float* __restrict__ p_b,
                    const float* __restrict__ A_log_b,
                    const float* __restrict__ u, const float* __restrict__ xk1,
                    const float* __restrict__ key2, float* __restrict__ yacc)
{
    const int dir = blockIdx.z;
    const float* dlt = dir ? delta_b : delta_f;
    const float* p   = dir ? p_b : p_f;
    const float* Al  = dir ? A_log_b : A_log_f;
    const int b  = blockIdx.y;
    const int d0 = blockIdx.x * 16;
    const int tid = threadIdx.x;
    const int n  = tid & 15, dl = tid >> 4;   // scan roles
    const int lj = tid & 15, lq = tid >> 4;   // staging roles

    __shared__ float sD[2][CH][16], sU[2][CH][16], sB[2][CH][16], sC[2][CH][16];
    __shared__ float sY[CH][16];

    float rD[4], rU[4], rB[4], rC[4];

    auto gload = [&](int c) {
        #pragma unroll
        for (int i = 0; i < 4; ++i) {
            int q = lq + 16 * i;
            int l = dir ? (L_ - 1 - (c * CH + q)) : (c * CH + q);
            size_t row = (size_t)(b * L_ + l);
            rD[i] = dlt[row * DI_ + d0 + lj];
            rU[i] = u[row * DI_ + d0 + lj];
            rB[i] = p[row * 64 + 32 + lj];
            rC[i] = p[row * 64 + 48 + lj];
        }
    };
    auto swrite = [&](int bf) {
        #pragma unroll
        for (int i = 0; i < 4; ++i) {
            int q = lq + 16 * i;
            sD[bf][q][lj] = rD[i];
            sU[bf][q][lj] = rU[i];
            sB[bf][q][lj] = rB[i];
            sC[bf][q][lj] = rC[i];
        }
    };

    gload(0);
    swrite(0);
    __syncthreads();

    const float An = -expf(Al[n]);
    float s = xk1[b * DI_ + d0 + dl] * key2[n];

    for (int c = 0; c < NCH; ++c) {
        int bf = c & 1;
        if (c + 1 < NCH) gload(c + 1);       // issue early, hide under scan

        #pragma unroll 8
        for (int q = 0; q < CH; ++q) {
            float dv = sD[bf][q][dl];
            float uv = sU[bf][q][dl];
            float Bv = sB[bf][q][n];
            float Cv = sC[bf][q][n];
            float dA = expf(An * dv);
            s = fmaf(dA, s, dv * Bv * uv);
            float part = s * Cv;
            part += __shfl_xor(part, 1, 16);
            part += __shfl_xor(part, 2, 16);
            part += __shfl_xor(part, 4, 16);
            part += __shfl_xor(part, 8, 16);
            if (n == 0) sY[q][dl] = part;
        }
        __syncthreads();
        if (c + 1 < NCH) swrite(bf ^ 1);
        // bulk flush (atomic: fwd+bwd blocks hit the same addresses)
        #pragma unroll
        for (int i = 0; i < 4; ++i) {
            int q = lq + 16 * i;
            int l = dir ? (L_ - 1 - (c * CH + q)) : (c * CH + q);
            atomicAdd(&yacc[(size_t)(b * L_ + l) * DI_ + d0 + lj], sY[q][lj]);
        }
        __syncthreads();
    }
}

// ---------------- spatial scan over channel axis d ----------------
__global__ __launch_bounds__(256)
void spatial_scan(const float* __restrict__ S1b, const float* __restrict__ S2b,
                  const float* __restrict__ Bs, const float* __restrict__ Cs,
                  const float* __restrict__ A_s_log, const float* __restrict__ s0sp,
                  float* __restrict__ yacc)
{
    int wave = threadIdx.x >> 6;
    int lane = threadIdx.x & 63;
    int r = blockIdx.x * 4 + wave;
    float s1 = S1b[r], s2 = S2b[r];
    int dbase = lane * 16;

    float a[16], bb[16];
    float Aloc = 1.f, Bloc = 0.f;
    #pragma unroll
    for (int j = 0; j < 16; ++j) {
        int d = dbase + j;
        float As = -expf(A_s_log[d]);
        float av = expf(s1 * As);
        float bv = s2 * Bs[(size_t)r * DI_ + d];
        a[j] = av; bb[j] = bv;
        Bloc = fmaf(av, Bloc, bv);
        Aloc *= av;
    }
    #pragma unroll
    for (int off = 1; off < 64; off <<= 1) {
        float Ap = __shfl_up(Aloc, off, 64);
        float Bp = __shfl_up(Bloc, off, 64);
        if (lane >= off) { Bloc = fmaf(Aloc, Bp, Bloc); Aloc *= Ap; }
    }
    float Aex = __shfl_up(Aloc, 1, 64);
    float Bex = __shfl_up(Bloc, 1, 64);
    if (lane == 0) { Aex = 1.f; Bex = 0.f; }
    float s = fmaf(Aex, s0sp[r], Bex);
    #pragma unroll
    for (int j = 0; j < 16; ++j) {
        int d = dbase + j;
        s = fmaf(a[j], s, bb[j]);
        yacc[(size_t)r * DI_ + d] += s * Cs[(size_t)r * DI_ + d];
    }
}

// ---------------- launcher ----------------
static inline void launch_gemm(const float* A, const float* W, float* C, const float* bias,
                               int M, int N, int K, int lda, int ldw, int ldc, int mode,
                               hipStream_t stream)
{
    dim3 grid((N + BN - 1) / BN, (M + BM - 1) / BM);
    gemm_f32<<<grid, 256, 0, stream>>>(A, W, C, bias, M, N, K, lda, ldw, ldc, mode);
}

static inline void launch_gemm_mfma(const unsigned short* Ah, const unsigned short* Alo,
                                    const unsigned short* Bh, const unsigned short* Bl,
                                    float* C, int M, int N, int K, hipStream_t stream)
{
    dim3 grid(N / SBN, M / SBM);
    gemm_split_mfma<<<grid, 256, 0, stream>>>(Ah, Alo, Bh, Bl, C, M, N, K);
}

extern "C" void kernel_launch(void* const* d_in, const int* in_sizes, int n_in,
                              void* d_out, int out_size, void* d_ws, size_t ws_size,
                              hipStream_t stream)
{
    const float* x         = (const float*)d_in[0];
    const float* x_key     = (const float*)d_in[1];
    const float* in_proj_w = (const float*)d_in[2];
    const float* conv_w    = (const float*)d_in[3];
    const float* conv_b    = (const float*)d_in[4];
    const float* x_proj_w  = (const float*)d_in[5];
    const float* x_proj_b_w= (const float*)d_in[6];
    const float* x_proj_s_w= (const float*)d_in[7];
    const float* dt_w      = (const float*)d_in[8];
    const float* dt_bias   = (const float*)d_in[9];
    const float* dt_b_w    = (const float*)d_in[10];
    const float* dt_b_bias = (const float*)d_in[11];
    const float* dt_s_w    = (const float*)d_in[12];
    const float* dt_s_bias = (const float*)d_in[13];
    const float* key1_w    = (const float*)d_in[14];
    const float* key2_w    = (const float*)d_in[15];
    const float* keys_w    = (const float*)d_in[16];
    const float* A_log     = (const float*)d_in[17];
    const float* A_b_log   = (const float*)d_in[18];
    const float* A_s_log   = (const float*)d_in[19];
    const float* D         = (const float*)d_in[20];
    const float* D_b       = (const float*)d_in[21];
    const float* D_s       = (const float*)d_in[22];
    const float* out_proj_w= (const float*)d_in[23];

    // ---- workspace carve-up (floats = round-1-validated footprint) ----
    char* base = (char*)d_ws;
    auto alloc_f = [&](size_t n) { float* p = (float*)base; base += n * 4; return p; };
    auto alloc_h = [&](size_t n) { unsigned short* p = (unsigned short*)base; base += n * 2; return p; };

    float* xz     = alloc_f((size_t)ROWS * 2 * DI_);
    float* u      = alloc_f((size_t)ROWS * DI_);
    float* p1     = alloc_f((size_t)ROWS * 64);
    float* p2     = alloc_f((size_t)ROWS * 64);
    float* drs    = alloc_f((size_t)ROWS * R_);
    float* Bs     = alloc_f((size_t)ROWS * DI_);
    float* Cs     = alloc_f((size_t)ROWS * DI_);
    float* delta  = alloc_f((size_t)ROWS * DI_);
    float* deltab = alloc_f((size_t)ROWS * DI_);
    float* S1     = alloc_f(ROWS);
    float* S2     = alloc_f(ROWS);
    float* xk1    = alloc_f((size_t)B_ * DI_);
    float* s0sp   = alloc_f((size_t)B_ * L_);
    float* yacc   = alloc_f((size_t)ROWS * DI_);
    // shared transposed-weight scratch (largest pair: 2*DI x DM)
    unsigned short* wscr_h = alloc_h((size_t)2 * DI_ * DM_);
    unsigned short* wscr_l = alloc_h((size_t)2 * DI_ * DM_);

    // bf16 aliases into dead/not-yet-live float buffers (stream-ordered safe):
    // xhi/xlo: consumed by GEMM 1; yacc first written at step 7.
    unsigned short* xhi = (unsigned short*)yacc;
    unsigned short* xlo = xhi + (size_t)ROWS * DM_;
    // uhi/ulo: consumed by Bs/Cs GEMMs; delta/deltab first written after.
    unsigned short* uhi = (unsigned short*)delta;
    unsigned short* ulo = (unsigned short*)deltab;
    // yhi/ylo: written after scans; delta/deltab dead then.
    unsigned short* yhi = (unsigned short*)delta;
    unsigned short* ylo = (unsigned short*)deltab;

    float* out = (float*)d_out;
    dim3 tblk(32, 8);

    // 1. xz = x @ in_proj_w           (MFMA split)
    split_f32<<<(ROWS * DM_ / 4 + 255) / 256, 256, 0, stream>>>(x, xhi, xlo, ROWS * DM_ / 4);
    split_transpose<<<dim3(2 * DI_ / 32, DM_ / 32), tblk, 0, stream>>>(in_proj_w, 2 * DI_, DM_, 2 * DI_, wscr_h, wscr_l);
    launch_gemm_mfma(xhi, xlo, wscr_h, wscr_l, xz, ROWS, 2 * DI_, DM_, stream);
    // 2. u = silu(conv(xc) + b)
    conv_silu<<<(ROWS * DI_) / 256, 256, 0, stream>>>(xz, conv_w, conv_b, u);
    split_f32<<<(ROWS * DI_ / 4 + 255) / 256, 256, 0, stream>>>(u, uhi, ulo, ROWS * DI_ / 4);
    // 3. projections (small -> fp32 VALU GEMM; big Bs/Cs -> MFMA split)
    launch_gemm(u, x_proj_w,   p1,  nullptr, ROWS, 64, DI_, DI_, 64, 64, 0, stream);
    launch_gemm(u, x_proj_b_w, p2,  nullptr, ROWS, 64, DI_, DI_, 64, 64, 0, stream);
    launch_gemm(u, x_proj_s_w, drs, nullptr, ROWS, R_, DI_, DI_, R_ + 2 * DI_, R_, 0, stream);
    split_transpose<<<dim3(DI_ / 32, DI_ / 32), tblk, 0, stream>>>(x_proj_s_w + 32, R_ + 2 * DI_, DI_, DI_, wscr_h, wscr_l);
    launch_gemm_mfma(uhi, ulo, wscr_h, wscr_l, Bs, ROWS, DI_, DI_, stream);
    split_transpose<<<dim3(DI_ / 32, DI_ / 32), tblk, 0, stream>>>(x_proj_s_w + 32 + DI_, R_ + 2 * DI_, DI_, DI_, wscr_h, wscr_l);
    launch_gemm_mfma(uhi, ulo, wscr_h, wscr_l, Cs, ROWS, DI_, DI_, stream);
    // 4. delta = softplus(dr @ dt_w + bias)   (overwrites uhi/ulo aliases - now dead)
    launch_gemm(p1, dt_w,   delta,  dt_bias,   ROWS, DI_, R_, 64, DI_, DI_, 1, stream);
    launch_gemm(p2, dt_b_w, deltab, dt_b_bias, ROWS, DI_, R_, 64, DI_, DI_, 1, stream);
    // 5. spatial scalars (delta_s never materialized)
    spatial_scalars<<<ROWS, 256, 0, stream>>>(drs, dt_s_w, dt_s_bias, u, S1, S2);
    // 6. initial states
    launch_gemm(x_key, key1_w, xk1,  nullptr, B_, DI_, DM_, DM_, DI_, DI_, 0, stream);
    launch_gemm(x_key, keys_w, s0sp, nullptr, B_, L_,  DM_, DM_, L_,  L_,  0, stream);
    // 7. yacc = res + u*(D+Db+Ds)   (overwrites xhi/xlo aliases - now dead)
    init_yacc<<<(ROWS * DI_) / 256, 256, 0, stream>>>(xz, u, D, D_b, D_s, yacc);
    // 8. temporal scans (both directions, one launch)
    {
        dim3 grid(DI_ / 16, B_, 2);
        temporal_scan2<<<grid, 256, 0, stream>>>(delta, p1, A_log, deltab, p2, A_b_log,
                                                 u, xk1, key2_w, yacc);
    }
    // 9. spatial scan over d
    spatial_scan<<<ROWS / 4, 256, 0, stream>>>(S1, S2, Bs, Cs, A_s_log, s0sp, yacc);
    // 10. out = yacc @ out_proj_w    (MFMA split; yhi/ylo alias dead delta/deltab)
    split_f32<<<(ROWS * DI_ / 4 + 255) / 256, 256, 0, stream>>>(yacc, yhi, ylo, ROWS * DI_ / 4);
    split_transpose<<<dim3(DM_ / 32, DI_ / 32), tblk, 0, stream>>>(out_proj_w, DM_, DI_, DM_, wscr_h, wscr_l);
    launch_gemm_mfma(yhi, ylo, wscr_h, wscr_l, out, ROWS, DM_, DI_, stream);
}

// Round 8
// 670.217 us; speedup vs baseline: 2.7766x; 1.9958x over previous
//
#include <hip/hip_runtime.h>
#include <cstddef>
#include <cstdint>

// Problem constants
#define B_   16
#define L_   256
#define DM_  512
#define DI_  1024
#define N_   16
#define R_   32
#define K_   4
#define ROWS (B_ * L_)          // 4096
#define PP_  256                // fused projection width (64 p1 | 64 p2 | 32 drs | pad)

typedef __attribute__((ext_vector_type(8))) short bf16x8;
typedef __attribute__((ext_vector_type(4))) float f32x4;

__device__ inline unsigned short f2bf(float x) {
    unsigned u = __float_as_uint(x);
    unsigned r = u + 0x7FFFu + ((u >> 16) & 1u);
    return (unsigned short)(r >> 16);
}
__device__ inline float bf2f(unsigned short h) {
    return __uint_as_float(((unsigned)h) << 16);
}

// ---------------- generic fp32 GEMM (wide-N only now): C = A @ W (+softplus) ----------------
#define BM 128
#define BN 128
#define BK 16

__global__ __launch_bounds__(256)
void gemm_f32(const float* __restrict__ A, const float* __restrict__ W,
              float* __restrict__ C, const float* __restrict__ bias,
              int M, int N, int K, int lda, int ldw, int ldc, int mode)
{
    __shared__ float As[BK][BM + 4];
    __shared__ float Ws[BK][BN + 4];
    const int tid = threadIdx.x;
    const int bn = blockIdx.x * BN;
    const int bm = blockIdx.y * BM;

    const int arow = tid >> 2;
    const int ak   = (tid & 3) * 4;
    const int wrow = tid >> 4;
    const int wc   = (tid & 15) * 8;
    const int tx = tid & 15, ty = tid >> 4;

    float acc[8][8];
    #pragma unroll
    for (int i = 0; i < 8; ++i)
        #pragma unroll
        for (int j = 0; j < 8; ++j) acc[i][j] = 0.f;

    for (int kt = 0; kt < K; kt += BK) {
        #pragma unroll
        for (int h = 0; h < 2; ++h) {
            int r = arow + h * 64;
            int grow = bm + r;
            float4 v = make_float4(0.f, 0.f, 0.f, 0.f);
            if (grow < M)
                v = *reinterpret_cast<const float4*>(A + (size_t)grow * lda + kt + ak);
            As[ak + 0][r] = v.x; As[ak + 1][r] = v.y;
            As[ak + 2][r] = v.z; As[ak + 3][r] = v.w;
        }
        #pragma unroll
        for (int h = 0; h < 2; ++h) {
            int col = wc + h * 4;
            int gcol = bn + col;
            float4 v;
            if (gcol + 3 < N) {
                v = *reinterpret_cast<const float4*>(W + (size_t)(kt + wrow) * ldw + gcol);
            } else {
                float t0 = (gcol + 0 < N) ? W[(size_t)(kt + wrow) * ldw + gcol + 0] : 0.f;
                float t1 = (gcol + 1 < N) ? W[(size_t)(kt + wrow) * ldw + gcol + 1] : 0.f;
                float t2 = (gcol + 2 < N) ? W[(size_t)(kt + wrow) * ldw + gcol + 2] : 0.f;
                float t3 = (gcol + 3 < N) ? W[(size_t)(kt + wrow) * ldw + gcol + 3] : 0.f;
                v = make_float4(t0, t1, t2, t3);
            }
            *reinterpret_cast<float4*>(&Ws[wrow][col]) = v;
        }
        __syncthreads();
        #pragma unroll
        for (int k = 0; k < BK; ++k) {
            float av[8], wv[8];
            #pragma unroll
            for (int i = 0; i < 8; ++i) av[i] = As[k][ty * 8 + i];
            #pragma unroll
            for (int j = 0; j < 8; ++j) wv[j] = Ws[k][tx * 8 + j];
            #pragma unroll
            for (int i = 0; i < 8; ++i)
                #pragma unroll
                for (int j = 0; j < 8; ++j)
                    acc[i][j] = fmaf(av[i], wv[j], acc[i][j]);
        }
        __syncthreads();
    }

    #pragma unroll
    for (int i = 0; i < 8; ++i) {
        int r = bm + ty * 8 + i;
        if (r >= M) break;
        #pragma unroll
        for (int j = 0; j < 8; ++j) {
            int cc = bn + tx * 8 + j;
            if (cc < N) {
                float v = acc[i][j];
                if (mode == 1) {
                    v += bias[cc];
                    v = fmaxf(v, 0.f) + log1pf(expf(-fabsf(v)));
                }
                C[(size_t)r * ldc + cc] = v;
            }
        }
    }
}

// ---------------- split-bf16 MFMA GEMM: C = (Ahi+Alo) @ W, W transposed hi/lo ----------------
#define SBM 128
#define SBN 128
#define SBK 32
#define SLDK 40   // padded LDS row (bf16): 80B rows -> 2-way conflicts only (free)

__global__ __launch_bounds__(256)
void gemm_split_mfma(const unsigned short* __restrict__ Ahi, const unsigned short* __restrict__ Alo,
                     const unsigned short* __restrict__ Bthi, const unsigned short* __restrict__ Btlo,
                     float* __restrict__ C, int M, int N, int K)
{
    __shared__ unsigned short sAh[SBM][SLDK], sAl[SBM][SLDK];
    __shared__ unsigned short sBh[SBN][SLDK], sBl[SBN][SLDK];
    const int tid = threadIdx.x;
    const int bm = blockIdx.y * SBM;
    const int bn = blockIdx.x * SBN;
    const int w = tid >> 6, lane = tid & 63;
    const int wr = w >> 1, wc = w & 1;
    const int lr = lane & 15, kg = lane >> 4;   // kg = k-group 0..3

    f32x4 acc[4][4];
    #pragma unroll
    for (int i = 0; i < 4; ++i)
        #pragma unroll
        for (int j = 0; j < 4; ++j) acc[i][j] = (f32x4){0.f, 0.f, 0.f, 0.f};

    const int srow0 = tid >> 2;          // 0..63
    const int sks   = (tid & 3) * 8;     // bf16 k-offset 0,8,16,24

    for (int kt = 0; kt < K; kt += SBK) {
        #pragma unroll
        for (int h = 0; h < 2; ++h) {
            int r = srow0 + h * 64;
            size_t ga = (size_t)(bm + r) * K + kt + sks;
            size_t gb = (size_t)(bn + r) * K + kt + sks;
            uint4 vah = *reinterpret_cast<const uint4*>(Ahi + ga);
            uint4 val = *reinterpret_cast<const uint4*>(Alo + ga);
            uint4 vbh = *reinterpret_cast<const uint4*>(Bthi + gb);
            uint4 vbl = *reinterpret_cast<const uint4*>(Btlo + gb);
            *reinterpret_cast<uint4*>(&sAh[r][sks]) = vah;
            *reinterpret_cast<uint4*>(&sAl[r][sks]) = val;
            *reinterpret_cast<uint4*>(&sBh[r][sks]) = vbh;
            *reinterpret_cast<uint4*>(&sBl[r][sks]) = vbl;
        }
        __syncthreads();

        bf16x8 ah[4], al[4], bh[4], bl[4];
        #pragma unroll
        for (int i = 0; i < 4; ++i) {
            ah[i] = *reinterpret_cast<const bf16x8*>(&sAh[wr * 64 + i * 16 + lr][kg * 8]);
            al[i] = *reinterpret_cast<const bf16x8*>(&sAl[wr * 64 + i * 16 + lr][kg * 8]);
            bh[i] = *reinterpret_cast<const bf16x8*>(&sBh[wc * 64 + i * 16 + lr][kg * 8]);
            bl[i] = *reinterpret_cast<const bf16x8*>(&sBl[wc * 64 + i * 16 + lr][kg * 8]);
        }
        #pragma unroll
        for (int i = 0; i < 4; ++i)
            #pragma unroll
            for (int j = 0; j < 4; ++j) {
                acc[i][j] = __builtin_amdgcn_mfma_f32_16x16x32_bf16(ah[i], bh[j], acc[i][j], 0, 0, 0);
                acc[i][j] = __builtin_amdgcn_mfma_f32_16x16x32_bf16(ah[i], bl[j], acc[i][j], 0, 0, 0);
                acc[i][j] = __builtin_amdgcn_mfma_f32_16x16x32_bf16(al[i], bh[j], acc[i][j], 0, 0, 0);
            }
        __syncthreads();
    }

    // C/D layout (m89-verified): col = lane&15, row = (lane>>4)*4 + reg
    #pragma unroll
    for (int i = 0; i < 4; ++i)
        #pragma unroll
        for (int j = 0; j < 4; ++j) {
            int col = bn + wc * 64 + j * 16 + lr;
            int rb  = bm + wr * 64 + i * 16 + kg * 4;
            #pragma unroll
            for (int r = 0; r < 4; ++r)
                C[(size_t)(rb + r) * N + col] = acc[i][j][r];
        }
}

// ---------------- fp32 -> (hi,lo) bf16, elementwise ----------------
__global__ __launch_bounds__(256)
void split_f32(const float* __restrict__ in, unsigned short* __restrict__ hi,
               unsigned short* __restrict__ lo, int n4)
{
    int i = blockIdx.x * 256 + threadIdx.x;
    if (i >= n4) return;
    float4 v = reinterpret_cast<const float4*>(in)[i];
    ushort4 h, l;
    h.x = f2bf(v.x); l.x = f2bf(v.x - bf2f(h.x));
    h.y = f2bf(v.y); l.y = f2bf(v.y - bf2f(h.y));
    h.z = f2bf(v.z); l.z = f2bf(v.z - bf2f(h.z));
    h.w = f2bf(v.w); l.w = f2bf(v.w - bf2f(h.w));
    reinterpret_cast<ushort4*>(hi)[i] = h;
    reinterpret_cast<ushort4*>(lo)[i] = l;
}

// ---------------- fp32 [rows][ldw] -> transposed (hi,lo) bf16 [cols][rows] ----------------
__global__ __launch_bounds__(256)
void split_transpose(const float* __restrict__ W, int ldw, int rows, int cols,
                     unsigned short* __restrict__ Thi, unsigned short* __restrict__ Tlo)
{
    __shared__ float t[32][33];
    int k0 = blockIdx.y * 32, n0 = blockIdx.x * 32;
    int tx = threadIdx.x, ty = threadIdx.y;      // 32 x 8
    #pragma unroll
    for (int i = 0; i < 4; ++i)
        t[ty + i * 8][tx] = W[(size_t)(k0 + ty + i * 8) * ldw + n0 + tx];
    __syncthreads();
    #pragma unroll
    for (int i = 0; i < 4; ++i) {
        int n = ty + i * 8;
        float v = t[tx][n];
        unsigned short h = f2bf(v);
        Thi[(size_t)(n0 + n) * rows + k0 + tx] = h;
        Tlo[(size_t)(n0 + n) * rows + k0 + tx] = f2bf(v - bf2f(h));
    }
}

// ---------------- concat proj weights -> transposed (hi,lo) bf16 [PP_][DI_] ----------------
__global__ __launch_bounds__(256)
void proj_wT(const float* __restrict__ xw, const float* __restrict__ xbw,
             const float* __restrict__ xsw,
             unsigned short* __restrict__ Th, unsigned short* __restrict__ Tl)
{
    int idx = blockIdx.x * 256 + threadIdx.x;   // PP_*DI_ = 262144
    int k = idx & (DI_ - 1);
    int j = idx >> 10;                          // 0..255
    float v = 0.f;
    if (j < 64)       v = xw[(size_t)k * 64 + j];
    else if (j < 128) v = xbw[(size_t)k * 64 + (j - 64)];
    else if (j < 160) v = xsw[(size_t)k * (R_ + 2 * DI_) + (j - 128)];
    unsigned short h = f2bf(v);
    Th[(size_t)j * DI_ + k] = h;
    Tl[(size_t)j * DI_ + k] = f2bf(v - bf2f(h));
}

// ---------------- fused initial states: xk1 = x_key@key1_w, s0sp = x_key@keys_w ----------------
__global__ __launch_bounds__(256)
void init_state(const float* __restrict__ x_key, const float* __restrict__ key1_w,
                const float* __restrict__ keys_w, float* __restrict__ xk1,
                float* __restrict__ s0sp)
{
    int b = blockIdx.y;
    int col = blockIdx.x * 256 + threadIdx.x;   // 0..1279
    __shared__ float xk[DM_];
    for (int i = threadIdx.x; i < DM_; i += 256) xk[i] = x_key[b * DM_ + i];
    __syncthreads();
    float acc = 0.f;
    if (col < DI_) {
        for (int k = 0; k < DM_; ++k)
            acc = fmaf(xk[k], key1_w[(size_t)k * DI_ + col], acc);
        xk1[b * DI_ + col] = acc;
    } else {
        int c = col - DI_;
        for (int k = 0; k < DM_; ++k)
            acc = fmaf(xk[k], keys_w[(size_t)k * L_ + c], acc);
        s0sp[b * L_ + c] = acc;
    }
}

// ---------------- causal depthwise conv (K=4) + SiLU ----------------
__global__ __launch_bounds__(256)
void conv_silu(const float* __restrict__ xz, const float* __restrict__ conv_w,
               const float* __restrict__ conv_b, float* __restrict__ u)
{
    int idx = blockIdx.x * 256 + threadIdx.x;
    if (idx >= ROWS * DI_) return;
    int d  = idx & (DI_ - 1);
    int rl = idx >> 10;
    int l  = rl & (L_ - 1);
    float acc = conv_b[d];
    #pragma unroll
    for (int k = 0; k < K_; ++k) {
        int ll = l + k - (K_ - 1);
        if (ll >= 0)
            acc = fmaf(xz[(size_t)(rl + k - (K_ - 1)) * (2 * DI_) + d], conv_w[d * K_ + k], acc);
    }
    u[idx] = acc / (1.f + expf(-acc));
}

// ---------------- yacc = res + u*(D + D_b + D_s) ----------------
__global__ __launch_bounds__(256)
void init_yacc(const float* __restrict__ xz, const float* __restrict__ u,
               const float* __restrict__ D, const float* __restrict__ Db,
               const float* __restrict__ Ds, float* __restrict__ yacc)
{
    int idx = blockIdx.x * 256 + threadIdx.x;
    if (idx >= ROWS * DI_) return;
    int d = idx & (DI_ - 1);
    int row = idx >> 10;
    yacc[idx] = xz[(size_t)row * (2 * DI_) + DI_ + d] + u[idx] * (D[d] + Db[d] + Ds[d]);
}

// ---------------- spatial scalars (drs now at pp col 128, stride PP_) ----------------
__global__ __launch_bounds__(256)
void spatial_scalars(const float* __restrict__ pp, const float* __restrict__ Wt,
                     const float* __restrict__ bias, const float* __restrict__ u,
                     float* __restrict__ S1, float* __restrict__ S2)
{
    int r = blockIdx.x;
    int tid = threadIdx.x;
    __shared__ float drsh[R_];
    if (tid < R_) drsh[tid] = pp[(size_t)r * PP_ + 128 + tid];
    __syncthreads();
    float s1 = 0.f, s2 = 0.f;
    #pragma unroll
    for (int j = 0; j < 4; ++j) {
        int d = tid + 256 * j;
        float acc = bias[d];
        #pragma unroll
        for (int k = 0; k < R_; ++k)
            acc = fmaf(drsh[k], Wt[k * DI_ + d], acc);
        float sp = fmaxf(acc, 0.f) + log1pf(expf(-fabsf(acc)));
        s1 += sp;
        s2 = fmaf(sp, u[(size_t)r * DI_ + d], s2);
    }
    #pragma unroll
    for (int off = 32; off; off >>= 1) {
        s1 += __shfl_down(s1, off, 64);
        s2 += __shfl_down(s2, off, 64);
    }
    __shared__ float red[2][4];
    int wave = tid >> 6, lane = tid & 63;
    if (lane == 0) { red[0][wave] = s1; red[1][wave] = s2; }
    __syncthreads();
    if (tid == 0) {
        S1[r] = red[0][0] + red[0][1] + red[0][2] + red[0][3];
        S2[r] = red[1][0] + red[1][1] + red[1][2] + red[1][3];
    }
}

// ---------------- temporal scans, LDS-chunked + double-buffered, both dirs in one launch ----------------
#define CH 64
#define NCH (L_ / CH)

__global__ __launch_bounds__(256)
void temporal_scan2(const float* __restrict__ delta_f, const float* __restrict__ delta_b,
                    const float* __restrict__ pp,
                    const float* __restrict__ A_log_f, const float* __restrict__ A_log_b,
                    const float* __restrict__ u, const float* __restrict__ xk1,
                    const float* __restrict__ key2, float* __restrict__ yacc)
{
    const int dir = blockIdx.z;
    const float* dlt = dir ? delta_b : delta_f;
    const float* Al  = dir ? A_log_b : A_log_f;
    const int Boff = dir ? 96 : 32;      // pp col offsets (p2 at 64, B at +32, C at +48)
    const int Coff = dir ? 112 : 48;
    const int b  = blockIdx.y;
    const int d0 = blockIdx.x * 16;
    const int tid = threadIdx.x;
    const int n  = tid & 15, dl = tid >> 4;   // scan roles
    const int lj = tid & 15, lq = tid >> 4;   // staging roles

    __shared__ float sD[2][CH][16], sU[2][CH][16], sB[2][CH][16], sC[2][CH][16];
    __shared__ float sY[CH][16];

    float rD[4], rU[4], rB[4], rC[4];

    auto gload = [&](int c) {
        #pragma unroll
        for (int i = 0; i < 4; ++i) {
            int q = lq + 16 * i;
            int l = dir ? (L_ - 1 - (c * CH + q)) : (c * CH + q);
            size_t row = (size_t)(b * L_ + l);
            rD[i] = dlt[row * DI_ + d0 + lj];
            rU[i] = u[row * DI_ + d0 + lj];
            rB[i] = pp[row * PP_ + Boff + lj];
            rC[i] = pp[row * PP_ + Coff + lj];
        }
    };
    auto swrite = [&](int bf) {
        #pragma unroll
        for (int i = 0; i < 4; ++i) {
            int q = lq + 16 * i;
            sD[bf][q][lj] = rD[i];
            sU[bf][q][lj] = rU[i];
            sB[bf][q][lj] = rB[i];
            sC[bf][q][lj] = rC[i];
        }
    };

    gload(0);
    swrite(0);
    __syncthreads();

    const float An = -expf(Al[n]);
    float s = xk1[b * DI_ + d0 + dl] * key2[n];

    for (int c = 0; c < NCH; ++c) {
        int bf = c & 1;
        if (c + 1 < NCH) gload(c + 1);       // issue early, hide under scan

        #pragma unroll 8
        for (int q = 0; q < CH; ++q) {
            float dv = sD[bf][q][dl];
            float uv = sU[bf][q][dl];
            float Bv = sB[bf][q][n];
            float Cv = sC[bf][q][n];
            float dA = expf(An * dv);
            s = fmaf(dA, s, dv * Bv * uv);
            float part = s * Cv;
            part += __shfl_xor(part, 1, 16);
            part += __shfl_xor(part, 2, 16);
            part += __shfl_xor(part, 4, 16);
            part += __shfl_xor(part, 8, 16);
            if (n == 0) sY[q][dl] = part;
        }
        __syncthreads();
        if (c + 1 < NCH) swrite(bf ^ 1);
        // bulk flush (atomic: fwd+bwd blocks hit the same addresses)
        #pragma unroll
        for (int i = 0; i < 4; ++i) {
            int q = lq + 16 * i;
            int l = dir ? (L_ - 1 - (c * CH + q)) : (c * CH + q);
            atomicAdd(&yacc[(size_t)(b * L_ + l) * DI_ + d0 + lj], sY[q][lj]);
        }
        __syncthreads();
    }
}

// ---------------- spatial scan over channel axis d ----------------
__global__ __launch_bounds__(256)
void spatial_scan(const float* __restrict__ S1b, const float* __restrict__ S2b,
                  const float* __restrict__ Bs, const float* __restrict__ Cs,
                  const float* __restrict__ A_s_log, const float* __restrict__ s0sp,
                  float* __restrict__ yacc)
{
    int wave = threadIdx.x >> 6;
    int lane = threadIdx.x & 63;
    int r = blockIdx.x * 4 + wave;
    float s1 = S1b[r], s2 = S2b[r];
    int dbase = lane * 16;

    float a[16], bb[16];
    float Aloc = 1.f, Bloc = 0.f;
    #pragma unroll
    for (int j = 0; j < 16; ++j) {
        int d = dbase + j;
        float As = -expf(A_s_log[d]);
        float av = expf(s1 * As);
        float bv = s2 * Bs[(size_t)r * DI_ + d];
        a[j] = av; bb[j] = bv;
        Bloc = fmaf(av, Bloc, bv);
        Aloc *= av;
    }
    #pragma unroll
    for (int off = 1; off < 64; off <<= 1) {
        float Ap = __shfl_up(Aloc, off, 64);
        float Bp = __shfl_up(Bloc, off, 64);
        if (lane >= off) { Bloc = fmaf(Aloc, Bp, Bloc); Aloc *= Ap; }
    }
    float Aex = __shfl_up(Aloc, 1, 64);
    float Bex = __shfl_up(Bloc, 1, 64);
    if (lane == 0) { Aex = 1.f; Bex = 0.f; }
    float s = fmaf(Aex, s0sp[r], Bex);
    #pragma unroll
    for (int j = 0; j < 16; ++j) {
        int d = dbase + j;
        s = fmaf(a[j], s, bb[j]);
        yacc[(size_t)r * DI_ + d] += s * Cs[(size_t)r * DI_ + d];
    }
}

// ---------------- launcher ----------------
static inline void launch_gemm(const float* A, const float* W, float* C, const float* bias,
                               int M, int N, int K, int lda, int ldw, int ldc, int mode,
                               hipStream_t stream)
{
    dim3 grid((N + BN - 1) / BN, (M + BM - 1) / BM);
    gemm_f32<<<grid, 256, 0, stream>>>(A, W, C, bias, M, N, K, lda, ldw, ldc, mode);
}

static inline void launch_gemm_mfma(const unsigned short* Ah, const unsigned short* Alo,
                                    const unsigned short* Bh, const unsigned short* Bl,
                                    float* C, int M, int N, int K, hipStream_t stream)
{
    dim3 grid(N / SBN, M / SBM);
    gemm_split_mfma<<<grid, 256, 0, stream>>>(Ah, Alo, Bh, Bl, C, M, N, K);
}

extern "C" void kernel_launch(void* const* d_in, const int* in_sizes, int n_in,
                              void* d_out, int out_size, void* d_ws, size_t ws_size,
                              hipStream_t stream)
{
    const float* x         = (const float*)d_in[0];
    const float* x_key     = (const float*)d_in[1];
    const float* in_proj_w = (const float*)d_in[2];
    const float* conv_w    = (const float*)d_in[3];
    const float* conv_b    = (const float*)d_in[4];
    const float* x_proj_w  = (const float*)d_in[5];
    const float* x_proj_b_w= (const float*)d_in[6];
    const float* x_proj_s_w= (const float*)d_in[7];
    const float* dt_w      = (const float*)d_in[8];
    const float* dt_bias   = (const float*)d_in[9];
    const float* dt_b_w    = (const float*)d_in[10];
    const float* dt_b_bias = (const float*)d_in[11];
    const float* dt_s_w    = (const float*)d_in[12];
    const float* dt_s_bias = (const float*)d_in[13];
    const float* key1_w    = (const float*)d_in[14];
    const float* key2_w    = (const float*)d_in[15];
    const float* keys_w    = (const float*)d_in[16];
    const float* A_log     = (const float*)d_in[17];
    const float* A_b_log   = (const float*)d_in[18];
    const float* A_s_log   = (const float*)d_in[19];
    const float* D         = (const float*)d_in[20];
    const float* D_b       = (const float*)d_in[21];
    const float* D_s       = (const float*)d_in[22];
    const float* out_proj_w= (const float*)d_in[23];

    // ---- workspace carve-up ----
    char* base = (char*)d_ws;
    auto alloc_f = [&](size_t n) { float* p = (float*)base; base += n * 4; return p; };
    auto alloc_h = [&](size_t n) { unsigned short* p = (unsigned short*)base; base += n * 2; return p; };

    float* xz     = alloc_f((size_t)ROWS * 2 * DI_);
    float* u      = alloc_f((size_t)ROWS * DI_);
    float* pp     = alloc_f((size_t)ROWS * PP_);     // fused p1|p2|drs|pad
    float* Bs     = alloc_f((size_t)ROWS * DI_);
    float* Cs     = alloc_f((size_t)ROWS * DI_);
    float* delta  = alloc_f((size_t)ROWS * DI_);
    float* deltab = alloc_f((size_t)ROWS * DI_);
    float* S1     = alloc_f(ROWS);
    float* S2     = alloc_f(ROWS);
    float* xk1    = alloc_f((size_t)B_ * DI_);
    float* s0sp   = alloc_f((size_t)B_ * L_);
    float* yacc   = alloc_f((size_t)ROWS * DI_);
    // shared transposed-weight scratch (largest pair: 2*DI x DM)
    unsigned short* wscr_h = alloc_h((size_t)2 * DI_ * DM_);
    unsigned short* wscr_l = alloc_h((size_t)2 * DI_ * DM_);

    // bf16 aliases into dead/not-yet-live float buffers (stream-ordered safe):
    // xhi/xlo: consumed by GEMM 1; yacc first written at step 7.
    unsigned short* xhi = (unsigned short*)yacc;
    unsigned short* xlo = xhi + (size_t)ROWS * DM_;
    // uhi/ulo: consumed by proj/Bs/Cs GEMMs; delta/deltab first written after.
    unsigned short* uhi = (unsigned short*)delta;
    unsigned short* ulo = (unsigned short*)deltab;
    // yhi/ylo: written after scans; delta/deltab dead then.
    unsigned short* yhi = (unsigned short*)delta;
    unsigned short* ylo = (unsigned short*)deltab;

    float* out = (float*)d_out;
    dim3 tblk(32, 8);

    // 1. xz = x @ in_proj_w           (MFMA split)
    split_f32<<<(ROWS * DM_ / 4 + 255) / 256, 256, 0, stream>>>(x, xhi, xlo, ROWS * DM_ / 4);
    split_transpose<<<dim3(2 * DI_ / 32, DM_ / 32), tblk, 0, stream>>>(in_proj_w, 2 * DI_, DM_, 2 * DI_, wscr_h, wscr_l);
    launch_gemm_mfma(xhi, xlo, wscr_h, wscr_l, xz, ROWS, 2 * DI_, DM_, stream);
    // 2. u = silu(conv(xc) + b)
    conv_silu<<<(ROWS * DI_) / 256, 256, 0, stream>>>(xz, conv_w, conv_b, u);
    split_f32<<<(ROWS * DI_ / 4 + 255) / 256, 256, 0, stream>>>(u, uhi, ulo, ROWS * DI_ / 4);
    // 3a. fused narrow projections: pp = u @ [x_proj_w | x_proj_b_w | x_proj_s_w_dr] (MFMA)
    proj_wT<<<(PP_ * DI_) / 256, 256, 0, stream>>>(x_proj_w, x_proj_b_w, x_proj_s_w, wscr_h, wscr_l);
    launch_gemm_mfma(uhi, ulo, wscr_h, wscr_l, pp, ROWS, PP_, DI_, stream);
    // 3b. big projections Bs/Cs (MFMA)
    split_transpose<<<dim3(DI_ / 32, DI_ / 32), tblk, 0, stream>>>(x_proj_s_w + 32, R_ + 2 * DI_, DI_, DI_, wscr_h, wscr_l);
    launch_gemm_mfma(uhi, ulo, wscr_h, wscr_l, Bs, ROWS, DI_, DI_, stream);
    split_transpose<<<dim3(DI_ / 32, DI_ / 32), tblk, 0, stream>>>(x_proj_s_w + 32 + DI_, R_ + 2 * DI_, DI_, DI_, wscr_h, wscr_l);
    launch_gemm_mfma(uhi, ulo, wscr_h, wscr_l, Cs, ROWS, DI_, DI_, stream);
    // 4. delta = softplus(dr @ dt_w + bias)   (A = pp cols 0..31 / 64..95; overwrites uhi/ulo - now dead)
    launch_gemm(pp,      dt_w,   delta,  dt_bias,   ROWS, DI_, R_, PP_, DI_, DI_, 1, stream);
    launch_gemm(pp + 64, dt_b_w, deltab, dt_b_bias, ROWS, DI_, R_, PP_, DI_, DI_, 1, stream);
    // 5. spatial scalars (drs at pp col 128)
    spatial_scalars<<<ROWS, 256, 0, stream>>>(pp, dt_s_w, dt_s_bias, u, S1, S2);
    // 6. initial states (fused small GEMMs)
    {
        dim3 grid((DI_ + L_) / 256, B_);
        init_state<<<grid, 256, 0, stream>>>(x_key, key1_w, keys_w, xk1, s0sp);
    }
    // 7. yacc = res + u*(D+Db+Ds)   (overwrites xhi/xlo aliases - now dead)
    init_yacc<<<(ROWS * DI_) / 256, 256, 0, stream>>>(xz, u, D, D_b, D_s, yacc);
    // 8. temporal scans (both directions, one launch)
    {
        dim3 grid(DI_ / 16, B_, 2);
        temporal_scan2<<<grid, 256, 0, stream>>>(delta, deltab, pp, A_log, A_b_log,
                                                 u, xk1, key2_w, yacc);
    }
    // 9. spatial scan over d
    spatial_scan<<<ROWS / 4, 256, 0, stream>>>(S1, S2, Bs, Cs, A_s_log, s0sp, yacc);
    // 10. out = yacc @ out_proj_w    (MFMA split; yhi/ylo alias dead delta/deltab)
    split_f32<<<(ROWS * DI_ / 4 + 255) / 256, 256, 0, stream>>>(yacc, yhi, ylo, ROWS * DI_ / 4);
    split_transpose<<<dim3(DM_ / 32, DI_ / 32), tblk, 0, stream>>>(out_proj_w, DM_, DI_, DM_, wscr_h, wscr_l);
    launch_gemm_mfma(yhi, ylo, wscr_h, wscr_l, out, ROWS, DM_, DI_, stream);
}

// Round 13
// 580.224 us; speedup vs baseline: 3.2073x; 1.1551x over previous
//
#include <hip/hip_runtime.h>
#include <cstddef>
#include <cstdint>

// Problem constants
#define B_   16
#define L_   256
#define DM_  512
#define DI_  1024
#define N_   16
#define R_   32
#define K_   4
#define ROWS (B_ * L_)          // 4096
#define PP_  256                // fused projection width (64 p1 | 64 p2 | 32 drs | pad)

typedef __attribute__((ext_vector_type(8))) short bf16x8;
typedef __attribute__((ext_vector_type(4))) float f32x4;

__device__ inline unsigned short f2bf(float x) {
    unsigned u = __float_as_uint(x);
    unsigned r = u + 0x7FFFu + ((u >> 16) & 1u);
    return (unsigned short)(r >> 16);
}
__device__ inline float bf2f(unsigned short h) {
    return __uint_as_float(((unsigned)h) << 16);
}

// sum over each 16-lane DPP row; row_shr accumulates toward HIGHER lanes,
// so the full row sum lands in lane 15 of each row (n==15). [AMD cross-lane blog]
__device__ inline float rowsum16(float x) {
    x += __uint_as_float(__builtin_amdgcn_update_dpp(0, __float_as_uint(x), 0x118, 0xf, 0xf, true)); // row_shr:8
    x += __uint_as_float(__builtin_amdgcn_update_dpp(0, __float_as_uint(x), 0x114, 0xf, 0xf, true)); // row_shr:4
    x += __uint_as_float(__builtin_amdgcn_update_dpp(0, __float_as_uint(x), 0x112, 0xf, 0xf, true)); // row_shr:2
    x += __uint_as_float(__builtin_amdgcn_update_dpp(0, __float_as_uint(x), 0x111, 0xf, 0xf, true)); // row_shr:1
    return x;
}

// ---------------- generic fp32 GEMM: C = A @ W (+softplus) ----------------
#define BM 128
#define BN 128
#define BK 16

__global__ __launch_bounds__(256)
void gemm_f32(const float* __restrict__ A, const float* __restrict__ W,
              float* __restrict__ C, const float* __restrict__ bias,
              int M, int N, int K, int lda, int ldw, int ldc, int mode)
{
    __shared__ float As[BK][BM + 4];
    __shared__ float Ws[BK][BN + 4];
    const int tid = threadIdx.x;
    const int bn = blockIdx.x * BN;
    const int bm = blockIdx.y * BM;

    const int arow = tid >> 2;
    const int ak   = (tid & 3) * 4;
    const int wrow = tid >> 4;
    const int wc   = (tid & 15) * 8;
    const int tx = tid & 15, ty = tid >> 4;

    float acc[8][8];
    #pragma unroll
    for (int i = 0; i < 8; ++i)
        #pragma unroll
        for (int j = 0; j < 8; ++j) acc[i][j] = 0.f;

    for (int kt = 0; kt < K; kt += BK) {
        #pragma unroll
        for (int h = 0; h < 2; ++h) {
            int r = arow + h * 64;
            int grow = bm + r;
            float4 v = make_float4(0.f, 0.f, 0.f, 0.f);
            if (grow < M)
                v = *reinterpret_cast<const float4*>(A + (size_t)grow * lda + kt + ak);
            As[ak + 0][r] = v.x; As[ak + 1][r] = v.y;
            As[ak + 2][r] = v.z; As[ak + 3][r] = v.w;
        }
        #pragma unroll
        for (int h = 0; h < 2; ++h) {
            int col = wc + h * 4;
            int gcol = bn + col;
            float4 v;
            if (gcol + 3 < N) {
                v = *reinterpret_cast<const float4*>(W + (size_t)(kt + wrow) * ldw + gcol);
            } else {
                float t0 = (gcol + 0 < N) ? W[(size_t)(kt + wrow) * ldw + gcol + 0] : 0.f;
                float t1 = (gcol + 1 < N) ? W[(size_t)(kt + wrow) * ldw + gcol + 1] : 0.f;
                float t2 = (gcol + 2 < N) ? W[(size_t)(kt + wrow) * ldw + gcol + 2] : 0.f;
                float t3 = (gcol + 3 < N) ? W[(size_t)(kt + wrow) * ldw + gcol + 3] : 0.f;
                v = make_float4(t0, t1, t2, t3);
            }
            *reinterpret_cast<float4*>(&Ws[wrow][col]) = v;
        }
        __syncthreads();
        #pragma unroll
        for (int k = 0; k < BK; ++k) {
            float av[8], wv[8];
            #pragma unroll
            for (int i = 0; i < 8; ++i) av[i] = As[k][ty * 8 + i];
            #pragma unroll
            for (int j = 0; j < 8; ++j) wv[j] = Ws[k][tx * 8 + j];
            #pragma unroll
            for (int i = 0; i < 8; ++i)
                #pragma unroll
                for (int j = 0; j < 8; ++j)
                    acc[i][j] = fmaf(av[i], wv[j], acc[i][j]);
        }
        __syncthreads();
    }

    #pragma unroll
    for (int i = 0; i < 8; ++i) {
        int r = bm + ty * 8 + i;
        if (r >= M) break;
        #pragma unroll
        for (int j = 0; j < 8; ++j) {
            int cc = bn + tx * 8 + j;
            if (cc < N) {
                float v = acc[i][j];
                if (mode == 1) {
                    v += bias[cc];
                    v = fmaxf(v, 0.f) + log1pf(__expf(-fabsf(v)));
                }
                C[(size_t)r * ldc + cc] = v;
            }
        }
    }
}

// ---------------- split-bf16 MFMA GEMM: C = (Ahi+Alo) @ W, W transposed hi/lo ----------------
#define SBM 128
#define SBN 128
#define SBK 32
#define SLDK 40   // padded LDS row (bf16): 80B rows -> 2-way conflicts only (free)

__global__ __launch_bounds__(256)
void gemm_split_mfma(const unsigned short* __restrict__ Ahi, const unsigned short* __restrict__ Alo,
                     const unsigned short* __restrict__ Bthi, const unsigned short* __restrict__ Btlo,
                     float* __restrict__ C, int M, int N, int K)
{
    __shared__ unsigned short sAh[SBM][SLDK], sAl[SBM][SLDK];
    __shared__ unsigned short sBh[SBN][SLDK], sBl[SBN][SLDK];
    const int tid = threadIdx.x;
    const int bm = blockIdx.y * SBM;
    const int bn = blockIdx.x * SBN;
    const int w = tid >> 6, lane = tid & 63;
    const int wr = w >> 1, wc = w & 1;
    const int lr = lane & 15, kg = lane >> 4;   // kg = k-group 0..3

    f32x4 acc[4][4];
    #pragma unroll
    for (int i = 0; i < 4; ++i)
        #pragma unroll
        for (int j = 0; j < 4; ++j) acc[i][j] = (f32x4){0.f, 0.f, 0.f, 0.f};

    const int srow0 = tid >> 2;          // 0..63
    const int sks   = (tid & 3) * 8;     // bf16 k-offset 0,8,16,24

    for (int kt = 0; kt < K; kt += SBK) {
        #pragma unroll
        for (int h = 0; h < 2; ++h) {
            int r = srow0 + h * 64;
            size_t ga = (size_t)(bm + r) * K + kt + sks;
            size_t gb = (size_t)(bn + r) * K + kt + sks;
            uint4 vah = *reinterpret_cast<const uint4*>(Ahi + ga);
            uint4 val = *reinterpret_cast<const uint4*>(Alo + ga);
            uint4 vbh = *reinterpret_cast<const uint4*>(Bthi + gb);
            uint4 vbl = *reinterpret_cast<const uint4*>(Btlo + gb);
            *reinterpret_cast<uint4*>(&sAh[r][sks]) = vah;
            *reinterpret_cast<uint4*>(&sAl[r][sks]) = val;
            *reinterpret_cast<uint4*>(&sBh[r][sks]) = vbh;
            *reinterpret_cast<uint4*>(&sBl[r][sks]) = vbl;
        }
        __syncthreads();

        bf16x8 ah[4], al[4], bh[4], bl[4];
        #pragma unroll
        for (int i = 0; i < 4; ++i) {
            ah[i] = *reinterpret_cast<const bf16x8*>(&sAh[wr * 64 + i * 16 + lr][kg * 8]);
            al[i] = *reinterpret_cast<const bf16x8*>(&sAl[wr * 64 + i * 16 + lr][kg * 8]);
            bh[i] = *reinterpret_cast<const bf16x8*>(&sBh[wc * 64 + i * 16 + lr][kg * 8]);
            bl[i] = *reinterpret_cast<const bf16x8*>(&sBl[wc * 64 + i * 16 + lr][kg * 8]);
        }
        #pragma unroll
        for (int i = 0; i < 4; ++i)
            #pragma unroll
            for (int j = 0; j < 4; ++j) {
                acc[i][j] = __builtin_amdgcn_mfma_f32_16x16x32_bf16(ah[i], bh[j], acc[i][j], 0, 0, 0);
                acc[i][j] = __builtin_amdgcn_mfma_f32_16x16x32_bf16(ah[i], bl[j], acc[i][j], 0, 0, 0);
                acc[i][j] = __builtin_amdgcn_mfma_f32_16x16x32_bf16(al[i], bh[j], acc[i][j], 0, 0, 0);
            }
        __syncthreads();
    }

    // C/D layout (m89-verified): col = lane&15, row = (lane>>4)*4 + reg
    #pragma unroll
    for (int i = 0; i < 4; ++i)
        #pragma unroll
        for (int j = 0; j < 4; ++j) {
            int col = bn + wc * 64 + j * 16 + lr;
            int rb  = bm + wr * 64 + i * 16 + kg * 4;
            #pragma unroll
            for (int r = 0; r < 4; ++r)
                C[(size_t)(rb + r) * N + col] = acc[i][j][r];
        }
}

// ---------------- fp32 -> (hi,lo) bf16, elementwise ----------------
__global__ __launch_bounds__(256)
void split_f32(const float* __restrict__ in, unsigned short* __restrict__ hi,
               unsigned short* __restrict__ lo, int n4)
{
    int i = blockIdx.x * 256 + threadIdx.x;
    if (i >= n4) return;
    float4 v = reinterpret_cast<const float4*>(in)[i];
    ushort4 h, l;
    h.x = f2bf(v.x); l.x = f2bf(v.x - bf2f(h.x));
    h.y = f2bf(v.y); l.y = f2bf(v.y - bf2f(h.y));
    h.z = f2bf(v.z); l.z = f2bf(v.z - bf2f(h.z));
    h.w = f2bf(v.w); l.w = f2bf(v.w - bf2f(h.w));
    reinterpret_cast<ushort4*>(hi)[i] = h;
    reinterpret_cast<ushort4*>(lo)[i] = l;
}

// ---------------- fp32 [rows][ldw] -> transposed (hi,lo) bf16 [cols][rows] ----------------
__global__ __launch_bounds__(256)
void split_transpose(const float* __restrict__ W, int ldw, int rows, int cols,
                     unsigned short* __restrict__ Thi, unsigned short* __restrict__ Tlo)
{
    __shared__ float t[32][33];
    int k0 = blockIdx.y * 32, n0 = blockIdx.x * 32;
    int tx = threadIdx.x, ty = threadIdx.y;      // 32 x 8
    #pragma unroll
    for (int i = 0; i < 4; ++i)
        t[ty + i * 8][tx] = W[(size_t)(k0 + ty + i * 8) * ldw + n0 + tx];
    __syncthreads();
    #pragma unroll
    for (int i = 0; i < 4; ++i) {
        int n = ty + i * 8;
        float v = t[tx][n];
        unsigned short h = f2bf(v);
        Thi[(size_t)(n0 + n) * rows + k0 + tx] = h;
        Tlo[(size_t)(n0 + n) * rows + k0 + tx] = f2bf(v - bf2f(h));
    }
}

// ---------------- concat proj weights -> transposed (hi,lo) bf16 [PP_][DI_] ----------------
__global__ __launch_bounds__(256)
void proj_wT(const float* __restrict__ xw, const float* __restrict__ xbw,
             const float* __restrict__ xsw,
             unsigned short* __restrict__ Th, unsigned short* __restrict__ Tl)
{
    int idx = blockIdx.x * 256 + threadIdx.x;   // PP_*DI_ = 262144
    int k = idx & (DI_ - 1);
    int j = idx >> 10;                          // 0..255
    float v = 0.f;
    if (j < 64)       v = xw[(size_t)k * 64 + j];
    else if (j < 128) v = xbw[(size_t)k * 64 + (j - 64)];
    else if (j < 160) v = xsw[(size_t)k * (R_ + 2 * DI_) + (j - 128)];
    unsigned short h = f2bf(v);
    Th[(size_t)j * DI_ + k] = h;
    Tl[(size_t)j * DI_ + k] = f2bf(v - bf2f(h));
}

// ---------------- fused initial states: xk1 = x_key@key1_w, s0sp = x_key@keys_w ----------------
__global__ __launch_bounds__(256)
void init_state(const float* __restrict__ x_key, const float* __restrict__ key1_w,
                const float* __restrict__ keys_w, float* __restrict__ xk1,
                float* __restrict__ s0sp)
{
    int b = blockIdx.y;
    int col = blockIdx.x * 256 + threadIdx.x;   // 0..1279
    __shared__ float xk[DM_];
    for (int i = threadIdx.x; i < DM_; i += 256) xk[i] = x_key[b * DM_ + i];
    __syncthreads();
    float acc = 0.f;
    if (col < DI_) {
        for (int k = 0; k < DM_; ++k)
            acc = fmaf(xk[k], key1_w[(size_t)k * DI_ + col], acc);
        xk1[b * DI_ + col] = acc;
    } else {
        int c = col - DI_;
        for (int k = 0; k < DM_; ++k)
            acc = fmaf(xk[k], keys_w[(size_t)k * L_ + c], acc);
        s0sp[b * L_ + c] = acc;
    }
}

// ---------------- causal depthwise conv (K=4) + SiLU ----------------
__global__ __launch_bounds__(256)
void conv_silu(const float* __restrict__ xz, const float* __restrict__ conv_w,
               const float* __restrict__ conv_b, float* __restrict__ u)
{
    int idx = blockIdx.x * 256 + threadIdx.x;
    if (idx >= ROWS * DI_) return;
    int d  = idx & (DI_ - 1);
    int rl = idx >> 10;
    int l  = rl & (L_ - 1);
    float acc = conv_b[d];
    #pragma unroll
    for (int k = 0; k < K_; ++k) {
        int ll = l + k - (K_ - 1);
        if (ll >= 0)
            acc = fmaf(xz[(size_t)(rl + k - (K_ - 1)) * (2 * DI_) + d], conv_w[d * K_ + k], acc);
    }
    u[idx] = acc / (1.f + __expf(-acc));
}

// ---------------- yacc = res + u*(D + D_b + D_s) ----------------
__global__ __launch_bounds__(256)
void init_yacc(const float* __restrict__ xz, const float* __restrict__ u,
               const float* __restrict__ D, const float* __restrict__ Db,
               const float* __restrict__ Ds, float* __restrict__ yacc)
{
    int idx = blockIdx.x * 256 + threadIdx.x;
    if (idx >= ROWS * DI_) return;
    int d = idx & (DI_ - 1);
    int row = idx >> 10;
    yacc[idx] = xz[(size_t)row * (2 * DI_) + DI_ + d] + u[idx] * (D[d] + Db[d] + Ds[d]);
}

// ---------------- spatial scalars (drs at pp col 128, stride PP_) ----------------
__global__ __launch_bounds__(256)
void spatial_scalars(const float* __restrict__ pp, const float* __restrict__ Wt,
                     const float* __restrict__ bias, const float* __restrict__ u,
                     float* __restrict__ S1, float* __restrict__ S2)
{
    int r = blockIdx.x;
    int tid = threadIdx.x;
    __shared__ float drsh[R_];
    if (tid < R_) drsh[tid] = pp[(size_t)r * PP_ + 128 + tid];
    __syncthreads();
    float s1 = 0.f, s2 = 0.f;
    #pragma unroll
    for (int j = 0; j < 4; ++j) {
        int d = tid + 256 * j;
        float acc = bias[d];
        #pragma unroll
        for (int k = 0; k < R_; ++k)
            acc = fmaf(drsh[k], Wt[k * DI_ + d], acc);
        float sp = fmaxf(acc, 0.f) + log1pf(__expf(-fabsf(acc)));
        s1 += sp;
        s2 = fmaf(sp, u[(size_t)r * DI_ + d], s2);
    }
    #pragma unroll
    for (int off = 32; off; off >>= 1) {
        s1 += __shfl_down(s1, off, 64);
        s2 += __shfl_down(s2, off, 64);
    }
    __shared__ float red[2][4];
    int wave = tid >> 6, lane = tid & 63;
    if (lane == 0) { red[0][wave] = s1; red[1][wave] = s2; }
    __syncthreads();
    if (tid == 0) {
        S1[r] = red[0][0] + red[0][1] + red[0][2] + red[0][3];
        S2[r] = red[1][0] + red[1][1] + red[1][2] + red[1][3];
    }
}

// ---------------- temporal scans v3: float4 LDS packing + DPP reduce ----------------
#define CH 32
#define NCH (L_ / CH)   // 8

__global__ __launch_bounds__(256)
void temporal_scan3(const float* __restrict__ delta_f, const float* __restrict__ delta_b,
                    const float* __restrict__ pp,
                    const float* __restrict__ A_log_f, const float* __restrict__ A_log_b,
                    const float* __restrict__ u, const float* __restrict__ xk1,
                    const float* __restrict__ key2, float* __restrict__ yacc)
{
    const int dir = blockIdx.z;
    const float* dlt = dir ? delta_b : delta_f;
    const float* Al  = dir ? A_log_b : A_log_f;
    const int Boff = dir ? 96 : 32;
    const int Coff = dir ? 112 : 48;
    const int b  = blockIdx.y;
    const int d0 = blockIdx.x * 16;
    const int tid = threadIdx.x;
    const int n  = tid & 15, dl = tid >> 4;   // scan roles (n = DPP row position)
    const int lj = tid & 15, lq = tid >> 4;   // staging roles (lq = q2 pair index)

    __shared__ float4 sDU[2][CH / 2][16];     // {dv0, uv0, dv1, uv1}
    __shared__ float4 sBC[2][CH / 2][16];     // {B0, C0, B1, C1}
    __shared__ float2 sY[CH / 2][16];

    float4 rDU, rBC;

    auto gload = [&](int c) {
        int t0 = c * CH + 2 * lq;
        int l0 = dir ? (L_ - 1 - t0) : t0;
        int l1 = dir ? (l0 - 1) : (l0 + 1);
        size_t r0 = (size_t)(b * L_ + l0);
        size_t r1 = (size_t)(b * L_ + l1);
        rDU.x = dlt[r0 * DI_ + d0 + lj];
        rDU.y = u[r0 * DI_ + d0 + lj];
        rDU.z = dlt[r1 * DI_ + d0 + lj];
        rDU.w = u[r1 * DI_ + d0 + lj];
        rBC.x = pp[r0 * PP_ + Boff + lj];
        rBC.y = pp[r0 * PP_ + Coff + lj];
        rBC.z = pp[r1 * PP_ + Boff + lj];
        rBC.w = pp[r1 * PP_ + Coff + lj];
    };
    auto swrite = [&](int bf) {
        sDU[bf][lq][lj] = rDU;
        sBC[bf][lq][lj] = rBC;
    };

    gload(0); swrite(0);
    __syncthreads();

    const float An = -__expf(Al[n]);
    float s = xk1[b * DI_ + d0 + dl] * key2[n];

    for (int c = 0; c < NCH; ++c) {
        int bf = c & 1;
        if (c + 1 < NCH) gload(c + 1);       // issue early, hide under scan

        #pragma unroll
        for (int q2 = 0; q2 < CH / 2; ++q2) {
            float4 du = sDU[bf][q2][dl];     // row-broadcast b128
            float4 bc = sBC[bf][q2][n];      // per-n b128
            float dA0 = __expf(An * du.x);
            s = fmaf(dA0, s, du.x * bc.x * du.y);
            float y0 = rowsum16(s * bc.y);
            float dA1 = __expf(An * du.z);
            s = fmaf(dA1, s, du.z * bc.z * du.w);
            float y1 = rowsum16(s * bc.w);
            if (n == 15) sY[q2][dl] = make_float2(y0, y1);   // row_shr sum lands in lane 15
        }
        __syncthreads();
        if (c + 1 < NCH) swrite(bf ^ 1);
        // bulk flush (atomic: fwd+bwd blocks hit the same addresses)
        {
            float2 v = sY[lq][lj];
            int t0 = c * CH + 2 * lq;
            int l0 = dir ? (L_ - 1 - t0) : t0;
            int l1 = dir ? (l0 - 1) : (l0 + 1);
            atomicAdd(&yacc[(size_t)(b * L_ + l0) * DI_ + d0 + lj], v.x);
            atomicAdd(&yacc[(size_t)(b * L_ + l1) * DI_ + d0 + lj], v.y);
        }
        __syncthreads();
    }
}

// ---------------- spatial scan over channel axis d ----------------
__global__ __launch_bounds__(256)
void spatial_scan(const float* __restrict__ S1b, const float* __restrict__ S2b,
                  const float* __restrict__ Bs, const float* __restrict__ Cs,
                  const float* __restrict__ A_s_log, const float* __restrict__ s0sp,
                  float* __restrict__ yacc)
{
    int wave = threadIdx.x >> 6;
    int lane = threadIdx.x & 63;
    int r = blockIdx.x * 4 + wave;
    float s1 = S1b[r], s2 = S2b[r];
    int dbase = lane * 16;

    float a[16], bb[16];
    float Aloc = 1.f, Bloc = 0.f;
    #pragma unroll
    for (int j = 0; j < 16; ++j) {
        int d = dbase + j;
        float As = -__expf(A_s_log[d]);
        float av = __expf(s1 * As);
        float bv = s2 * Bs[(size_t)r * DI_ + d];
        a[j] = av; bb[j] = bv;
        Bloc = fmaf(av, Bloc, bv);
        Aloc *= av;
    }
    #pragma unroll
    for (int off = 1; off < 64; off <<= 1) {
        float Ap = __shfl_up(Aloc, off, 64);
        float Bp = __shfl_up(Bloc, off, 64);
        if (lane >= off) { Bloc = fmaf(Aloc, Bp, Bloc); Aloc *= Ap; }
    }
    float Aex = __shfl_up(Aloc, 1, 64);
    float Bex = __shfl_up(Bloc, 1, 64);
    if (lane == 0) { Aex = 1.f; Bex = 0.f; }
    float s = fmaf(Aex, s0sp[r], Bex);
    #pragma unroll
    for (int j = 0; j < 16; ++j) {
        int d = dbase + j;
        s = fmaf(a[j], s, bb[j]);
        yacc[(size_t)r * DI_ + d] += s * Cs[(size_t)r * DI_ + d];
    }
}

// ---------------- launcher ----------------
static inline void launch_gemm(const float* A, const float* W, float* C, const float* bias,
                               int M, int N, int K, int lda, int ldw, int ldc, int mode,
                               hipStream_t stream)
{
    dim3 grid((N + BN - 1) / BN, (M + BM - 1) / BM);
    gemm_f32<<<grid, 256, 0, stream>>>(A, W, C, bias, M, N, K, lda, ldw, ldc, mode);
}

static inline void launch_gemm_mfma(const unsigned short* Ah, const unsigned short* Alo,
                                    const unsigned short* Bh, const unsigned short* Bl,
                                    float* C, int M, int N, int K, hipStream_t stream)
{
    dim3 grid(N / SBN, M / SBM);
    gemm_split_mfma<<<grid, 256, 0, stream>>>(Ah, Alo, Bh, Bl, C, M, N, K);
}

extern "C" void kernel_launch(void* const* d_in, const int* in_sizes, int n_in,
                              void* d_out, int out_size, void* d_ws, size_t ws_size,
                              hipStream_t stream)
{
    const float* x         = (const float*)d_in[0];
    const float* x_key     = (const float*)d_in[1];
    const float* in_proj_w = (const float*)d_in[2];
    const float* conv_w    = (const float*)d_in[3];
    const float* conv_b    = (const float*)d_in[4];
    const float* x_proj_w  = (const float*)d_in[5];
    const float* x_proj_b_w= (const float*)d_in[6];
    const float* x_proj_s_w= (const float*)d_in[7];
    const float* dt_w      = (const float*)d_in[8];
    const float* dt_bias   = (const float*)d_in[9];
    const float* dt_b_w    = (const float*)d_in[10];
    const float* dt_b_bias = (const float*)d_in[11];
    const float* dt_s_w    = (const float*)d_in[12];
    const float* dt_s_bias = (const float*)d_in[13];
    const float* key1_w    = (const float*)d_in[14];
    const float* key2_w    = (const float*)d_in[15];
    const float* keys_w    = (const float*)d_in[16];
    const float* A_log     = (const float*)d_in[17];
    const float* A_b_log   = (const float*)d_in[18];
    const float* A_s_log   = (const float*)d_in[19];
    const float* D         = (const float*)d_in[20];
    const float* D_b       = (const float*)d_in[21];
    const float* D_s       = (const float*)d_in[22];
    const float* out_proj_w= (const float*)d_in[23];

    // ---- workspace carve-up ----
    char* base = (char*)d_ws;
    auto alloc_f = [&](size_t n) { float* p = (float*)base; base += n * 4; return p; };
    auto alloc_h = [&](size_t n) { unsigned short* p = (unsigned short*)base; base += n * 2; return p; };

    float* xz     = alloc_f((size_t)ROWS * 2 * DI_);
    float* u      = alloc_f((size_t)ROWS * DI_);
    float* pp     = alloc_f((size_t)ROWS * PP_);     // fused p1|p2|drs|pad
    float* Bs     = alloc_f((size_t)ROWS * DI_);
    float* Cs     = alloc_f((size_t)ROWS * DI_);
    float* delta  = alloc_f((size_t)ROWS * DI_);
    float* deltab = alloc_f((size_t)ROWS * DI_);
    float* S1     = alloc_f(ROWS);
    float* S2     = alloc_f(ROWS);
    float* xk1    = alloc_f((size_t)B_ * DI_);
    float* s0sp   = alloc_f((size_t)B_ * L_);
    float* yacc   = alloc_f((size_t)ROWS * DI_);
    // shared transposed-weight scratch (largest pair: 2*DI x DM)
    unsigned short* wscr_h = alloc_h((size_t)2 * DI_ * DM_);
    unsigned short* wscr_l = alloc_h((size_t)2 * DI_ * DM_);

    // bf16 aliases into dead/not-yet-live float buffers (stream-ordered safe):
    unsigned short* xhi = (unsigned short*)yacc;
    unsigned short* xlo = xhi + (size_t)ROWS * DM_;
    unsigned short* uhi = (unsigned short*)delta;
    unsigned short* ulo = (unsigned short*)deltab;
    unsigned short* yhi = (unsigned short*)delta;
    unsigned short* ylo = (unsigned short*)deltab;

    float* out = (float*)d_out;
    dim3 tblk(32, 8);

    // 1. xz = x @ in_proj_w           (MFMA split)
    split_f32<<<(ROWS * DM_ / 4 + 255) / 256, 256, 0, stream>>>(x, xhi, xlo, ROWS * DM_ / 4);
    split_transpose<<<dim3(2 * DI_ / 32, DM_ / 32), tblk, 0, stream>>>(in_proj_w, 2 * DI_, DM_, 2 * DI_, wscr_h, wscr_l);
    launch_gemm_mfma(xhi, xlo, wscr_h, wscr_l, xz, ROWS, 2 * DI_, DM_, stream);
    // 2. u = silu(conv(xc) + b)
    conv_silu<<<(ROWS * DI_) / 256, 256, 0, stream>>>(xz, conv_w, conv_b, u);
    split_f32<<<(ROWS * DI_ / 4 + 255) / 256, 256, 0, stream>>>(u, uhi, ulo, ROWS * DI_ / 4);
    // 3a. fused narrow projections: pp = u @ [x_proj_w | x_proj_b_w | x_proj_s_w_dr] (MFMA)
    proj_wT<<<(PP_ * DI_) / 256, 256, 0, stream>>>(x_proj_w, x_proj_b_w, x_proj_s_w, wscr_h, wscr_l);
    launch_gemm_mfma(uhi, ulo, wscr_h, wscr_l, pp, ROWS, PP_, DI_, stream);
    // 3b. big projections Bs/Cs (MFMA)
    split_transpose<<<dim3(DI_ / 32, DI_ / 32), tblk, 0, stream>>>(x_proj_s_w + 32, R_ + 2 * DI_, DI_, DI_, wscr_h, wscr_l);
    launch_gemm_mfma(uhi, ulo, wscr_h, wscr_l, Bs, ROWS, DI_, DI_, stream);
    split_transpose<<<dim3(DI_ / 32, DI_ / 32), tblk, 0, stream>>>(x_proj_s_w + 32 + DI_, R_ + 2 * DI_, DI_, DI_, wscr_h, wscr_l);
    launch_gemm_mfma(uhi, ulo, wscr_h, wscr_l, Cs, ROWS, DI_, DI_, stream);
    // 4. delta = softplus(dr @ dt_w + bias)
    launch_gemm(pp,      dt_w,   delta,  dt_bias,   ROWS, DI_, R_, PP_, DI_, DI_, 1, stream);
    launch_gemm(pp + 64, dt_b_w, deltab, dt_b_bias, ROWS, DI_, R_, PP_, DI_, DI_, 1, stream);
    // 5. spatial scalars (drs at pp col 128)
    spatial_scalars<<<ROWS, 256, 0, stream>>>(pp, dt_s_w, dt_s_bias, u, S1, S2);
    // 6. initial states (fused small GEMMs)
    {
        dim3 grid((DI_ + L_) / 256, B_);
        init_state<<<grid, 256, 0, stream>>>(x_key, key1_w, keys_w, xk1, s0sp);
    }
    // 7. yacc = res + u*(D+Db+Ds)
    init_yacc<<<(ROWS * DI_) / 256, 256, 0, stream>>>(xz, u, D, D_b, D_s, yacc);
    // 8. temporal scans (both directions, one launch)
    {
        dim3 grid(DI_ / 16, B_, 2);
        temporal_scan3<<<grid, 256, 0, stream>>>(delta, deltab, pp, A_log, A_b_log,
                                                 u, xk1, key2_w, yacc);
    }
    // 9. spatial scan over d
    spatial_scan<<<ROWS / 4, 256, 0, stream>>>(S1, S2, Bs, Cs, A_s_log, s0sp, yacc);
    // 10. out = yacc @ out_proj_w    (MFMA split; yhi/ylo alias dead delta/deltab)
    split_f32<<<(ROWS * DI_ / 4 + 255) / 256, 256, 0, stream>>>(yacc, yhi, ylo, ROWS * DI_ / 4);
    split_transpose<<<dim3(DM_ / 32, DI_ / 32), tblk, 0, stream>>>(out_proj_w, DM_, DI_, DM_, wscr_h, wscr_l);
    launch_gemm_mfma(yhi, ylo, wscr_h, wscr_l, out, ROWS, DM_, DI_, stream);
}